// Round 1
// baseline (2396.814 us; speedup 1.0000x reference)
//
#include <hip/hip_runtime.h>
#include <math.h>

// Problem constants
#define NB     16
#define HEADS  8
#define HD     64
#define EMBED  512
#define QL     512
#define KL     512

// ws layout (float offsets)
#define WS_QPROJ 0
#define WS_KPROJ 4194304
#define WS_VPROJ 8388608
#define WS_PE    12582912   // [1024][512]
#define WS_REL   13107200   // [1024][512]
#define WS_WOT   13631488   // [512][512] transposed Wo
// total 13893632 floats = ~55.6 MB

// ---------------------------------------------------------------- PE table
__global__ void pe_kernel(float* __restrict__ pe) {
    int j = blockIdx.x;        // 0..1023
    int i = threadIdx.x;       // 0..255
    // invf = 10000^(-i/256) = 2^(-i * log2(10000)/256)
    float invf = exp2f(-(float)i * (13.287712379549449f / 256.0f));
    float ang  = (float)j * invf;
    pe[j * 512 + i]       = sinf(ang);
    pe[j * 512 + 256 + i] = cosf(ang);
}

// ------------------------------------------------- rel = PE @ Wr^T  (1024x512x512)
__global__ __launch_bounds__(256) void rel_kernel(const float* __restrict__ pe,
                                                  const float* __restrict__ Wr,
                                                  float* __restrict__ rel) {
    __shared__ float At[64][68];
    __shared__ float Bt[64][68];
    int j0 = blockIdx.x * 64, e0 = blockIdx.y * 64;
    int tid = threadIdx.x;
    int tj = (tid >> 4) * 4;    // 0..60
    int te = (tid & 15) * 4;
    float acc[4][4] = {};
    for (int f0 = 0; f0 < 512; f0 += 64) {
        for (int i = 0; i < 16; ++i) {
            int idx = tid + 256 * i;       // 0..4095
            int r = idx >> 6, c = idx & 63;
            At[r][c] = pe[(j0 + r) * 512 + f0 + c];
            Bt[r][c] = Wr[(e0 + r) * 512 + f0 + c];
        }
        __syncthreads();
        for (int c4 = 0; c4 < 64; c4 += 4) {
            float4 a[4], b[4];
            for (int i = 0; i < 4; ++i) a[i] = *(const float4*)&At[tj + i][c4];
            for (int i = 0; i < 4; ++i) b[i] = *(const float4*)&Bt[te + i][c4];
            for (int i = 0; i < 4; ++i)
                for (int m = 0; m < 4; ++m)
                    acc[i][m] += a[i].x * b[m].x + a[i].y * b[m].y +
                                 a[i].z * b[m].z + a[i].w * b[m].w;
        }
        __syncthreads();
    }
    for (int i = 0; i < 4; ++i)
        for (int m = 0; m < 4; ++m)
            rel[(j0 + tj + i) * 512 + e0 + te + m] = acc[i][m];
}

// ---------------------------------------------------------- Wo transpose
__global__ __launch_bounds__(256) void wot_kernel(const float* __restrict__ Wo,
                                                  float* __restrict__ wot) {
    __shared__ float t[32][33];
    int bx = blockIdx.x & 15, by = blockIdx.x >> 4;
    int lx = threadIdx.x & 31, ly = threadIdx.x >> 5;  // 32 x 8
    for (int i = 0; i < 4; ++i)
        t[ly + 8 * i][lx] = Wo[(by * 32 + ly + 8 * i) * 512 + bx * 32 + lx];
    __syncthreads();
    for (int i = 0; i < 4; ++i)
        wot[(bx * 32 + ly + 8 * i) * 512 + by * 32 + lx] = t[lx][ly + 8 * i];
}

// ------------------------------------------------- q/k/v head projections
// out[n][h][t][d] = sum_dp in[n][t][h*64+dp] * W[d][dp]
__global__ __launch_bounds__(256) void proj_kernel(const float* __restrict__ query,
                                                   const float* __restrict__ keys,
                                                   const float* __restrict__ values,
                                                   const float* __restrict__ Wq,
                                                   const float* __restrict__ Wk,
                                                   const float* __restrict__ Wv,
                                                   float* __restrict__ ws) {
    __shared__ float Wl[3][64][68];
    __shared__ float inl[16][512];
    int n  = blockIdx.x >> 5;
    int t0 = (blockIdx.x & 31) * 16;
    int tid = threadIdx.x;
    for (int p = 0; p < 3; ++p) {
        const float* Wp = (p == 0) ? Wq : (p == 1) ? Wk : Wv;
        for (int i = 0; i < 16; ++i) {
            int idx = tid + 256 * i;       // 0..4095
            Wl[p][idx >> 6][idx & 63] = Wp[idx];
        }
    }
    int d = tid & 63, h1 = tid >> 6, h2 = h1 + 4;
    for (int p = 0; p < 3; ++p) {
        const float* src = (p == 0) ? query : (p == 1) ? keys : values;
        __syncthreads();
        for (int i = 0; i < 32; ++i) {
            int idx = tid + 256 * i;       // 0..8191
            int r = idx >> 9, c = idx & 511;
            inl[r][c] = src[(n * 512 + t0 + r) * 512 + c];
        }
        __syncthreads();
        float acc1[16] = {}, acc2[16] = {};
        for (int c4 = 0; c4 < 64; c4 += 4) {
            float4 w4 = *(const float4*)&Wl[p][d][c4];
            for (int r = 0; r < 16; ++r) {
                float4 a = *(const float4*)&inl[r][h1 * 64 + c4];
                float4 b = *(const float4*)&inl[r][h2 * 64 + c4];
                acc1[r] += w4.x * a.x + w4.y * a.y + w4.z * a.z + w4.w * a.w;
                acc2[r] += w4.x * b.x + w4.y * b.y + w4.z * b.z + w4.w * b.w;
            }
        }
        float* out = ws + p * 4194304;
        for (int r = 0; r < 16; ++r) {
            out[((n * 8 + h1) * 512 + t0 + r) * 64 + d] = acc1[r];
            out[((n * 8 + h2) * 512 + t0 + r) * 64 + d] = acc2[r];
        }
    }
}

// ------------------------------------------- fused scores+softmax+PV kernel
// one block per (n, h, q-tile of 32); 512 threads
__global__ __launch_bounds__(512) void attn_kernel(const float* __restrict__ ws,
                                                   const int* __restrict__ mask,
                                                   const float* __restrict__ u_bias,
                                                   const float* __restrict__ v_bias,
                                                   float* __restrict__ d_out) {
    __shared__ float qu[32][68];
    __shared__ float qv[32][68];
    __shared__ float kh[128][68];
    __shared__ float S[32][520];

    const float* qproj = ws + WS_QPROJ;
    const float* kproj = ws + WS_KPROJ;
    const float* vproj = ws + WS_VPROJ;
    const float* rel   = ws + WS_REL;
    float* outbuf = d_out;                  // [N][Q][512] — oh staging
    float* attn   = d_out + 4194304;        // [N][H][Q][K]

    int blk = blockIdx.x;
    int n  = blk >> 7;
    int h  = (blk >> 4) & 7;
    int q0 = (blk & 15) * 32;
    int tid = threadIdx.x;
    int nh = n * 8 + h;

    // P0: q tile + biases
    for (int i = 0; i < 4; ++i) {
        int idx = tid + 512 * i;            // 0..2047
        int qi = idx >> 6, d = idx & 63;
        float val = qproj[(nh * 512 + q0 + qi) * 64 + d];
        qu[qi][d] = val + u_bias[h * 64 + d];
        qv[qi][d] = val + v_bias[h * 64 + d];
    }
    __syncthreads();

    int qg = tid >> 5;      // 0..15  -> q rows qg*2, qg*2+1
    int kg = tid & 31;      // 0..31  -> cols kg + 32*j

    // P1: content scores -> S (write)
    for (int kt = 0; kt < 4; ++kt) {
        int k0 = kt * 128;
        for (int i = 0; i < 16; ++i) {
            int idx = tid + 512 * i;        // 0..8191
            int kk = idx >> 6, d = idx & 63;
            kh[kk][d] = kproj[(nh * 512 + k0 + kk) * 64 + d];
        }
        __syncthreads();
        float acc[2][4] = {};
        for (int c4 = 0; c4 < 64; c4 += 4) {
            float4 a0 = *(const float4*)&qu[qg * 2][c4];
            float4 a1 = *(const float4*)&qu[qg * 2 + 1][c4];
            for (int j = 0; j < 4; ++j) {
                float4 b = *(const float4*)&kh[kg + 32 * j][c4];
                acc[0][j] += a0.x * b.x + a0.y * b.y + a0.z * b.z + a0.w * b.w;
                acc[1][j] += a1.x * b.x + a1.y * b.y + a1.z * b.z + a1.w * b.w;
            }
        }
        for (int j = 0; j < 4; ++j) {
            S[qg * 2][k0 + kg + 32 * j]     = acc[0][j];
            S[qg * 2 + 1][k0 + kg + 32 * j] = acc[1][j];
        }
        __syncthreads();
    }

    // P2: position scores -> S (+=), Toeplitz: pos[q,k] = qv[q] . rel[q+512-k]
    for (int jt = 0; jt < 5; ++jt) {
        int jbase = q0 + 1 + jt * 128;
        for (int i = 0; i < 16; ++i) {
            int idx = tid + 512 * i;
            int jj = idx >> 6, d = idx & 63;
            int j = jbase + jj; if (j > 1023) j = 1023;   // clamped rows never used
            kh[jj][d] = rel[j * 512 + h * 64 + d];
        }
        __syncthreads();
        float acc[2][4] = {};
        for (int c4 = 0; c4 < 64; c4 += 4) {
            float4 a0 = *(const float4*)&qv[qg * 2][c4];
            float4 a1 = *(const float4*)&qv[qg * 2 + 1][c4];
            for (int j = 0; j < 4; ++j) {
                float4 b = *(const float4*)&kh[kg + 32 * j][c4];
                acc[0][j] += a0.x * b.x + a0.y * b.y + a0.z * b.z + a0.w * b.w;
                acc[1][j] += a1.x * b.x + a1.y * b.y + a1.z * b.z + a1.w * b.w;
            }
        }
        for (int a = 0; a < 2; ++a) {
            int ql = qg * 2 + a;
            for (int j = 0; j < 4; ++j) {
                int jj = kg + 32 * j;
                int k = ql + 511 - jt * 128 - jj;   // q+512 - (jbase+jj) + q0 offset folded
                if (k >= 0 && k < 512) S[ql][k] += acc[a][j];
            }
        }
        __syncthreads();
    }

    // P3: mask + scale + softmax; write attn; keep P in S
    {
        int wave = tid >> 6, lane = tid & 63;
        for (int i = 0; i < 4; ++i) {
            int r = wave + 8 * i;
            const int* mrow = mask + (n * 512 + q0 + r) * 512;
            float lg[8];
            float mx = -3.0e38f;
            for (int j = 0; j < 8; ++j) {
                int k = lane + 64 * j;
                float s = S[r][k];
                int m = mrow[k];
                float l = (m == 0) ? -1.25e19f : s * 0.125f;   // (-1e20)/8
                lg[j] = l;
                mx = fmaxf(mx, l);
            }
            for (int o = 32; o > 0; o >>= 1) mx = fmaxf(mx, __shfl_xor(mx, o, 64));
            float sum = 0.f;
            for (int j = 0; j < 8; ++j) { lg[j] = __expf(lg[j] - mx); sum += lg[j]; }
            for (int o = 32; o > 0; o >>= 1) sum += __shfl_xor(sum, o, 64);
            float inv = 1.0f / sum;
            float* arow = attn + ((long)(nh * 512) + q0 + r) * 512;
            for (int j = 0; j < 8; ++j) {
                int k = lane + 64 * j;
                float p = lg[j] * inv;
                S[r][k] = p;
                arow[k] = p;
            }
        }
    }
    __syncthreads();

    // P4: PV with 4-way k-split; partial reduce via LDS (reuse kh)
    float4 acc[4] = {{0,0,0,0},{0,0,0,0},{0,0,0,0},{0,0,0,0}};
    int sub = tid >> 7;            // 0..3 : kk range [sub*32, sub*32+32)
    int tt  = tid & 127;
    int dg  = tt & 15;             // float4 group in d
    int qB  = (tt >> 4) * 4;       // 4 q rows
    for (int kt = 0; kt < 4; ++kt) {
        int k0 = kt * 128;
        for (int i = 0; i < 16; ++i) {
            int idx = tid + 512 * i;
            int kk = idx >> 6, d = idx & 63;
            kh[kk][d] = vproj[(nh * 512 + k0 + kk) * 64 + d];
        }
        __syncthreads();
        for (int kk = sub * 32; kk < sub * 32 + 32; ++kk) {
            float4 v4 = *(const float4*)&kh[kk][dg * 4];
            int kglob = k0 + kk;
            for (int a = 0; a < 4; ++a) {
                float p = S[qB + a][kglob];
                acc[a].x += p * v4.x; acc[a].y += p * v4.y;
                acc[a].z += p * v4.z; acc[a].w += p * v4.w;
            }
        }
        __syncthreads();
    }
    float* red = &kh[0][0];   // 4*32*16*4 = 8192 floats <= 128*68
    for (int a = 0; a < 4; ++a)
        *(float4*)&red[((sub * 32 + qB + a) * 16 + dg) * 4] = acc[a];
    __syncthreads();
    {
        int qi = tid >> 4, dgf = tid & 15;
        float4 r0 = *(const float4*)&red[((0 * 32 + qi) * 16 + dgf) * 4];
        float4 r1 = *(const float4*)&red[((1 * 32 + qi) * 16 + dgf) * 4];
        float4 r2 = *(const float4*)&red[((2 * 32 + qi) * 16 + dgf) * 4];
        float4 r3 = *(const float4*)&red[((3 * 32 + qi) * 16 + dgf) * 4];
        float4 o;
        o.x = r0.x + r1.x + r2.x + r3.x;
        o.y = r0.y + r1.y + r2.y + r3.y;
        o.z = r0.z + r1.z + r2.z + r3.z;
        o.w = r0.w + r1.w + r2.w + r3.w;
        *(float4*)&outbuf[(long)(n * 512 + q0 + qi) * 512 + h * 64 + dgf * 4] = o;
    }
}

// --------------------------------------- out = oh @ Wo^T + bo (in-place rows)
__global__ __launch_bounds__(256) void wo_kernel(const float* __restrict__ wot,
                                                 const float* __restrict__ bo,
                                                 float* __restrict__ d_out) {
    __shared__ float ohl[32][516];
    float* outbuf = d_out;
    int r0 = blockIdx.x * 32;
    int tid = threadIdx.x;
    for (int i = 0; i < 64; ++i) {
        int idx = tid + 256 * i;       // 0..16383
        int r = idx >> 9, c = idx & 511;
        ohl[r][c] = outbuf[(long)(r0 + r) * 512 + c];
    }
    __syncthreads();
    int c1 = tid, c2 = tid + 256;
    float acc1[32] = {}, acc2[32] = {};
    for (int e = 0; e < 512; e += 4) {
        float w1[4], w2[4];
        for (int j = 0; j < 4; ++j) {
            w1[j] = wot[(e + j) * 512 + c1];
            w2[j] = wot[(e + j) * 512 + c2];
        }
        for (int r = 0; r < 32; ++r) {
            float4 a = *(const float4*)&ohl[r][e];
            acc1[r] += a.x * w1[0] + a.y * w1[1] + a.z * w1[2] + a.w * w1[3];
            acc2[r] += a.x * w2[0] + a.y * w2[1] + a.z * w2[2] + a.w * w2[3];
        }
    }
    float b1 = bo[c1], b2 = bo[c2];
    for (int r = 0; r < 32; ++r) {
        outbuf[(long)(r0 + r) * 512 + c1] = acc1[r] + b1;
        outbuf[(long)(r0 + r) * 512 + c2] = acc2[r] + b2;
    }
}

extern "C" void kernel_launch(void* const* d_in, const int* in_sizes, int n_in,
                              void* d_out, int out_size, void* d_ws, size_t ws_size,
                              hipStream_t stream) {
    const float* values = (const float*)d_in[0];
    const float* keys   = (const float*)d_in[1];
    const float* query  = (const float*)d_in[2];
    const int*   mask   = (const int*)d_in[3];
    const float* Wv     = (const float*)d_in[4];
    const float* Wk     = (const float*)d_in[5];
    const float* Wq     = (const float*)d_in[6];
    const float* Wr     = (const float*)d_in[7];
    const float* u_bias = (const float*)d_in[8];
    const float* v_bias = (const float*)d_in[9];
    const float* Wo     = (const float*)d_in[10];
    const float* bo     = (const float*)d_in[11];
    float* out = (float*)d_out;
    float* ws  = (float*)d_ws;

    float* pe  = ws + WS_PE;
    float* rel = ws + WS_REL;
    float* wot = ws + WS_WOT;

    hipLaunchKernelGGL(pe_kernel,   dim3(1024),   dim3(256), 0, stream, pe);
    hipLaunchKernelGGL(rel_kernel,  dim3(16, 8),  dim3(256), 0, stream, pe, Wr, rel);
    hipLaunchKernelGGL(wot_kernel,  dim3(256),    dim3(256), 0, stream, Wo, wot);
    hipLaunchKernelGGL(proj_kernel, dim3(512),    dim3(256), 0, stream,
                       query, keys, values, Wq, Wk, Wv, ws);
    hipLaunchKernelGGL(attn_kernel, dim3(2048),   dim3(512), 0, stream,
                       ws, mask, u_bias, v_bias, out);
    hipLaunchKernelGGL(wo_kernel,   dim3(256),    dim3(256), 0, stream, wot, bo, out);
}

// Round 2
// 381.803 us; speedup vs baseline: 6.2776x; 6.2776x over previous
//
#include <hip/hip_runtime.h>
#include <math.h>

// Problem constants
#define NB     16
#define HEADS  8
#define HD     64
#define EMBED  512
#define QL     512
#define KL     512

// ws layout (float-unit offsets)
#define WS_QU   0           // bf16 [16][8][512][64]  (2097152 floats)
#define WS_QV   2097152     // bf16 [16][8][512][64]
#define WS_KB   4194304     // bf16 [16][8][512][64]
#define WS_VT   6291456     // bf16 [16][8][64][512]  (v transposed)
#define WS_PE   8388608     // f32  [1024][512]
#define WS_RELB 8912896     // bf16 [8][1024][64]
#define WS_WOT  9175040     // f32  [512][512]
// total 9437184 floats = 37.7 MB

typedef __attribute__((ext_vector_type(8))) short bf16x8;
typedef __attribute__((ext_vector_type(4))) float f32x4;
typedef __attribute__((ext_vector_type(8))) unsigned short ushort8v;
typedef __attribute__((ext_vector_type(4))) unsigned short ushort4v;

#define MFMA16 __builtin_amdgcn_mfma_f32_16x16x32_bf16

static __device__ __forceinline__ short f2bf(float x) {
    unsigned u = __builtin_bit_cast(unsigned, x);
    u += 0x7fffu + ((u >> 16) & 1u);      // round-to-nearest-even
    return (short)(u >> 16);
}

// ---------------------------------------------------------------- PE table
__global__ void pe_kernel(float* __restrict__ pe) {
    int j = blockIdx.x;        // 0..1023
    int i = threadIdx.x;       // 0..255
    float invf = exp2f(-(float)i * (13.287712379549449f / 256.0f));
    float ang  = (float)j * invf;
    pe[j * 512 + i]       = sinf(ang);
    pe[j * 512 + 256 + i] = cosf(ang);
}

// ----------------------------------------- rel_b = bf16(PE @ Wr^T) per head
__global__ __launch_bounds__(256) void rel_kernel(const float* __restrict__ pe,
                                                  const float* __restrict__ Wr,
                                                  unsigned short* __restrict__ relb) {
    __shared__ float At[64][68];
    __shared__ float Bt[64][68];
    int j0 = blockIdx.x * 64, e0 = blockIdx.y * 64;
    int tid = threadIdx.x;
    int tj = (tid >> 4) * 4;
    int te = (tid & 15) * 4;
    float acc[4][4] = {};
    for (int f0 = 0; f0 < 512; f0 += 64) {
        for (int i = 0; i < 16; ++i) {
            int idx = tid + 256 * i;
            int r = idx >> 6, c = idx & 63;
            At[r][c] = pe[(j0 + r) * 512 + f0 + c];
            Bt[r][c] = Wr[(e0 + r) * 512 + f0 + c];
        }
        __syncthreads();
        for (int c4 = 0; c4 < 64; c4 += 4) {
            float4 a[4], b[4];
            for (int i = 0; i < 4; ++i) a[i] = *(const float4*)&At[tj + i][c4];
            for (int i = 0; i < 4; ++i) b[i] = *(const float4*)&Bt[te + i][c4];
            for (int i = 0; i < 4; ++i)
                for (int m = 0; m < 4; ++m)
                    acc[i][m] += a[i].x * b[m].x + a[i].y * b[m].y +
                                 a[i].z * b[m].z + a[i].w * b[m].w;
        }
        __syncthreads();
    }
    int e = e0 + te;
    int hh = e >> 6, dd = e & 63;
    for (int i = 0; i < 4; ++i) {
        ushort4v pk;
        for (int m = 0; m < 4; ++m) pk[m] = (unsigned short)f2bf(acc[i][m]);
        *(ushort4v*)&relb[(hh * 1024 + j0 + tj + i) * 64 + dd] = pk;
    }
}

// ---------------------------------------------------------- Wo transpose
__global__ __launch_bounds__(256) void wot_kernel(const float* __restrict__ Wo,
                                                  float* __restrict__ wot) {
    __shared__ float t[32][33];
    int bx = blockIdx.x & 15, by = blockIdx.x >> 4;
    int lx = threadIdx.x & 31, ly = threadIdx.x >> 5;
    for (int i = 0; i < 4; ++i)
        t[ly + 8 * i][lx] = Wo[(by * 32 + ly + 8 * i) * 512 + bx * 32 + lx];
    __syncthreads();
    for (int i = 0; i < 4; ++i)
        wot[(bx * 32 + ly + 8 * i) * 512 + by * 32 + lx] = t[lx][ly + 8 * i];
}

// ------------------------------------------------- q/k/v head projections
__global__ __launch_bounds__(256) void proj_kernel(const float* __restrict__ query,
                                                   const float* __restrict__ keys,
                                                   const float* __restrict__ values,
                                                   const float* __restrict__ Wq,
                                                   const float* __restrict__ Wk,
                                                   const float* __restrict__ Wv,
                                                   const float* __restrict__ u_bias,
                                                   const float* __restrict__ v_bias,
                                                   float* __restrict__ ws) {
    __shared__ float Wl[3][64][68];
    __shared__ float inl[16][512];
    int n  = blockIdx.x >> 5;
    int t0 = (blockIdx.x & 31) * 16;
    int tid = threadIdx.x;
    for (int p = 0; p < 3; ++p) {
        const float* Wp = (p == 0) ? Wq : (p == 1) ? Wk : Wv;
        for (int i = 0; i < 16; ++i) {
            int idx = tid + 256 * i;
            Wl[p][idx >> 6][idx & 63] = Wp[idx];
        }
    }
    int d = tid & 63, h1 = tid >> 6, h2 = h1 + 4;
    unsigned short* qu_b = (unsigned short*)(ws + WS_QU);
    unsigned short* qv_b = (unsigned short*)(ws + WS_QV);
    unsigned short* k_b  = (unsigned short*)(ws + WS_KB);
    unsigned short* vT_b = (unsigned short*)(ws + WS_VT);
    for (int p = 0; p < 3; ++p) {
        const float* src = (p == 0) ? query : (p == 1) ? keys : values;
        __syncthreads();
        for (int i = 0; i < 32; ++i) {
            int idx = tid + 256 * i;
            int r = idx >> 9, c = idx & 511;
            inl[r][c] = src[(n * 512 + t0 + r) * 512 + c];
        }
        __syncthreads();
        float acc1[16] = {}, acc2[16] = {};
        for (int c4 = 0; c4 < 64; c4 += 4) {
            float4 w4 = *(const float4*)&Wl[p][d][c4];
            for (int r = 0; r < 16; ++r) {
                float4 a = *(const float4*)&inl[r][h1 * 64 + c4];
                float4 b = *(const float4*)&inl[r][h2 * 64 + c4];
                acc1[r] += w4.x * a.x + w4.y * a.y + w4.z * a.z + w4.w * a.w;
                acc2[r] += w4.x * b.x + w4.y * b.y + w4.z * b.z + w4.w * b.w;
            }
        }
        if (p == 0) {
            for (int hs = 0; hs < 2; ++hs) {
                int h = hs ? h2 : h1;
                const float* acc = hs ? acc2 : acc1;
                float ub = u_bias[h * 64 + d], vb = v_bias[h * 64 + d];
                int nh = n * 8 + h;
                for (int r = 0; r < 16; ++r) {
                    qu_b[((nh * 512) + t0 + r) * 64 + d] = (unsigned short)f2bf(acc[r] + ub);
                    qv_b[((nh * 512) + t0 + r) * 64 + d] = (unsigned short)f2bf(acc[r] + vb);
                }
            }
        } else if (p == 1) {
            for (int hs = 0; hs < 2; ++hs) {
                int h = hs ? h2 : h1;
                const float* acc = hs ? acc2 : acc1;
                int nh = n * 8 + h;
                for (int r = 0; r < 16; ++r)
                    k_b[((nh * 512) + t0 + r) * 64 + d] = (unsigned short)f2bf(acc[r]);
            }
        } else {
            for (int hs = 0; hs < 2; ++hs) {
                int h = hs ? h2 : h1;
                const float* acc = hs ? acc2 : acc1;
                int nh = n * 8 + h;
                ushort8v p0, p1;
                for (int j = 0; j < 8; ++j) {
                    p0[j] = (unsigned short)f2bf(acc[j]);
                    p1[j] = (unsigned short)f2bf(acc[8 + j]);
                }
                *(ushort8v*)&vT_b[(nh * 64 + d) * 512 + t0]     = p0;
                *(ushort8v*)&vT_b[(nh * 64 + d) * 512 + t0 + 8] = p1;
            }
        }
    }
}

// ------------------------------------------- fused MFMA scores+softmax+PV
// one block per (n, h, q-tile of 64); 512 threads = 8 waves
__global__ __launch_bounds__(512) void attn_kernel(const float* __restrict__ ws,
                                                   const int* __restrict__ mask,
                                                   float* __restrict__ d_out) {
    __shared__ __align__(16) float S[64][516];            // 132096 B
    __shared__ __align__(16) unsigned short stage[128][64]; // 16384 B

    const unsigned short* qu_b = (const unsigned short*)(ws + WS_QU);
    const unsigned short* qv_b = (const unsigned short*)(ws + WS_QV);
    const unsigned short* k_b  = (const unsigned short*)(ws + WS_KB);
    const unsigned short* vT_b = (const unsigned short*)(ws + WS_VT);
    const unsigned short* relb = (const unsigned short*)(ws + WS_RELB);
    float* oh   = d_out;                 // [N][Q][512] staging
    float* attn = d_out + 4194304;       // [N][H][Q][K]

    int blk = blockIdx.x;
    int n  = blk >> 6;
    int h  = (blk >> 3) & 7;
    int q0 = (blk & 7) * 64;
    int nh = n * 8 + h;

    int tid  = threadIdx.x;
    int w    = tid >> 6, lane = tid & 63;
    int wq   = w >> 1, half = w & 1;
    int fr   = lane & 15, fg = lane >> 4;

    // ---- stage qu (rows 0-63) + qv (rows 64-127), hoist q fragments to regs
    for (int p = 0; p < 2; ++p) {
        int idx = tid + 512 * p;
        int row = idx >> 3, slot = idx & 7;
        const unsigned short* g = (row < 64)
            ? &qu_b[((nh * 512) + q0 + row) * 64 + slot * 8]
            : &qv_b[((nh * 512) + q0 + row - 64) * 64 + slot * 8];
        *(bf16x8*)&stage[row][((slot ^ (row & 7))) * 8] = *(const bf16x8*)g;
    }
    __syncthreads();
    bf16x8 qu_f[2], qv_f[2];
    {
        int ar = wq * 16 + fr;
#pragma unroll
        for (int s = 0; s < 2; ++s) {
            int sl = ((fg + s * 4) ^ (ar & 7)) * 8;
            qu_f[s] = *(const bf16x8*)&stage[ar][sl];
            qv_f[s] = *(const bf16x8*)&stage[64 + ar][sl];
        }
    }

    // ---- content scores: S[q][k] = (q+u) . k
    for (int kc = 0; kc < 4; ++kc) {
        int k0 = kc * 128;
        __syncthreads();
        for (int p = 0; p < 2; ++p) {
            int idx = tid + 512 * p;
            int row = idx >> 3, slot = idx & 7;
            const unsigned short* g = &k_b[((nh * 512) + k0 + row) * 64 + slot * 8];
            *(bf16x8*)&stage[row][((slot ^ (row & 7))) * 8] = *(const bf16x8*)g;
        }
        __syncthreads();
#pragma unroll
        for (int t = 0; t < 4; ++t) {
            f32x4 acc = {0.f, 0.f, 0.f, 0.f};
            int br = half * 64 + t * 16 + fr;
#pragma unroll
            for (int s = 0; s < 2; ++s) {
                bf16x8 bf = *(const bf16x8*)&stage[br][((fg + s * 4) ^ (br & 7)) * 8];
                acc = MFMA16(qu_f[s], bf, acc, 0, 0, 0);
            }
            int cc = k0 + br;       // k0 + half*64 + t*16 + fr
            int rb = wq * 16 + fg * 4;
#pragma unroll
            for (int i = 0; i < 4; ++i) S[rb + i][cc] = acc[i];
        }
    }

    // ---- position scores: S[r][k] += (q+v) . rel[j],  k = r + 511 - jj
    for (int jc = 0; jc < 5; ++jc) {
        __syncthreads();
        for (int p = 0; p < 2; ++p) {
            int idx = tid + 512 * p;
            int row = idx >> 3, slot = idx & 7;
            int j = q0 + 1 + jc * 128 + row;
            if (j > 1023) j = 1023;
            const unsigned short* g = &relb[(h * 1024 + j) * 64 + slot * 8];
            *(bf16x8*)&stage[row][((slot ^ (row & 7))) * 8] = *(const bf16x8*)g;
        }
        __syncthreads();
#pragma unroll
        for (int t = 0; t < 4; ++t) {
            f32x4 acc = {0.f, 0.f, 0.f, 0.f};
            int br = half * 64 + t * 16 + fr;
#pragma unroll
            for (int s = 0; s < 2; ++s) {
                bf16x8 bf = *(const bf16x8*)&stage[br][((fg + s * 4) ^ (br & 7)) * 8];
                acc = MFMA16(qv_f[s], bf, acc, 0, 0, 0);
            }
            int jj = jc * 128 + br;   // block-local j index
#pragma unroll
            for (int i = 0; i < 4; ++i) {
                int r = wq * 16 + fg * 4 + i;
                int k = r + 511 - jj;
                if ((unsigned)k < 512u) S[r][k] += acc[i];
            }
        }
    }

    // ---- mask + scale + softmax; write attn; leave P (f32) in S
    __syncthreads();
    for (int rr = 0; rr < 8; ++rr) {
        int r = w * 8 + rr;
        const int* mrow = mask + ((long)(n * 512 + q0 + r)) * 512;
        float lg[8];
        float mx = -3.0e38f;
#pragma unroll
        for (int j = 0; j < 8; ++j) {
            int k = lane + 64 * j;
            float s = S[r][k];
            int m = mrow[k];
            float l = (m == 0) ? -1.25e19f : s * 0.125f;
            lg[j] = l;
            mx = fmaxf(mx, l);
        }
        for (int o = 32; o > 0; o >>= 1) mx = fmaxf(mx, __shfl_xor(mx, o, 64));
        float sum = 0.f;
#pragma unroll
        for (int j = 0; j < 8; ++j) { lg[j] = __expf(lg[j] - mx); sum += lg[j]; }
        for (int o = 32; o > 0; o >>= 1) sum += __shfl_xor(sum, o, 64);
        float inv = 1.0f / sum;
        float* arow = attn + ((long)(nh * 512 + q0 + r)) * 512;
#pragma unroll
        for (int j = 0; j < 8; ++j) {
            int k = lane + 64 * j;
            float p = lg[j] * inv;
            S[r][k] = p;
            arow[k] = p;
        }
    }

    // ---- PV: oh[q][d] = P . v   (vT staged, P converted bf16 from S)
    f32x4 oacc[2] = {{0.f,0.f,0.f,0.f},{0.f,0.f,0.f,0.f}};
    for (int kc = 0; kc < 4; ++kc) {
        int k0 = kc * 128;
        __syncthreads();
        for (int p = 0; p < 2; ++p) {
            int idx = tid + 512 * p;
            int row = idx >> 3, slot = idx & 7;
            int dd = row & 63;
            int koff = (row >> 6) * 64 + slot * 8;
            const unsigned short* g = &vT_b[(nh * 64 + dd) * 512 + k0 + koff];
            *(bf16x8*)&stage[row][((slot ^ (row & 7))) * 8] = *(const bf16x8*)g;
        }
        __syncthreads();
#pragma unroll
        for (int sub = 0; sub < 2; ++sub) {
            bf16x8 pf[2];
#pragma unroll
            for (int s = 0; s < 2; ++s) {
                const float* sp = &S[wq * 16 + fr][k0 + sub * 64 + s * 32 + fg * 8];
                f32x4 a = *(const f32x4*)sp;
                f32x4 b = *(const f32x4*)(sp + 4);
                bf16x8 pk;
                pk[0] = f2bf(a.x); pk[1] = f2bf(a.y); pk[2] = f2bf(a.z); pk[3] = f2bf(a.w);
                pk[4] = f2bf(b.x); pk[5] = f2bf(b.y); pk[6] = f2bf(b.z); pk[7] = f2bf(b.w);
                pf[s] = pk;
            }
#pragma unroll
            for (int t = 0; t < 2; ++t) {
                int br = sub * 64 + half * 32 + t * 16 + fr;
#pragma unroll
                for (int s = 0; s < 2; ++s) {
                    bf16x8 bf = *(const bf16x8*)&stage[br][((fg + s * 4) ^ (br & 7)) * 8];
                    oacc[t] = MFMA16(pf[s], bf, oacc[t], 0, 0, 0);
                }
            }
        }
    }
#pragma unroll
    for (int t = 0; t < 2; ++t)
#pragma unroll
        for (int i = 0; i < 4; ++i)
            oh[((long)(n * 512 + q0 + wq * 16 + fg * 4 + i)) * 512 +
               h * 64 + half * 32 + t * 16 + fr] = oacc[t][i];
}

// --------------------------------------- out = oh @ Wo^T + bo (in-place rows)
__global__ __launch_bounds__(256) void wo_kernel(const float* __restrict__ wot,
                                                 const float* __restrict__ bo,
                                                 float* __restrict__ d_out) {
    __shared__ float ohl[32][516];
    float* outbuf = d_out;
    int r0 = blockIdx.x * 32;
    int tid = threadIdx.x;
    for (int i = 0; i < 64; ++i) {
        int idx = tid + 256 * i;
        int r = idx >> 9, c = idx & 511;
        ohl[r][c] = outbuf[(long)(r0 + r) * 512 + c];
    }
    __syncthreads();
    int c1 = tid, c2 = tid + 256;
    float acc1[32] = {}, acc2[32] = {};
    for (int e = 0; e < 512; e += 4) {
        float w1[4], w2[4];
        for (int j = 0; j < 4; ++j) {
            w1[j] = wot[(e + j) * 512 + c1];
            w2[j] = wot[(e + j) * 512 + c2];
        }
        for (int r = 0; r < 32; ++r) {
            float4 a = *(const float4*)&ohl[r][e];
            acc1[r] += a.x * w1[0] + a.y * w1[1] + a.z * w1[2] + a.w * w1[3];
            acc2[r] += a.x * w2[0] + a.y * w2[1] + a.z * w2[2] + a.w * w2[3];
        }
    }
    float b1 = bo[c1], b2 = bo[c2];
    for (int r = 0; r < 32; ++r) {
        outbuf[(long)(r0 + r) * 512 + c1] = acc1[r] + b1;
        outbuf[(long)(r0 + r) * 512 + c2] = acc2[r] + b2;
    }
}

extern "C" void kernel_launch(void* const* d_in, const int* in_sizes, int n_in,
                              void* d_out, int out_size, void* d_ws, size_t ws_size,
                              hipStream_t stream) {
    const float* values = (const float*)d_in[0];
    const float* keys   = (const float*)d_in[1];
    const float* query  = (const float*)d_in[2];
    const int*   mask   = (const int*)d_in[3];
    const float* Wv     = (const float*)d_in[4];
    const float* Wk     = (const float*)d_in[5];
    const float* Wq     = (const float*)d_in[6];
    const float* Wr     = (const float*)d_in[7];
    const float* u_bias = (const float*)d_in[8];
    const float* v_bias = (const float*)d_in[9];
    const float* Wo     = (const float*)d_in[10];
    const float* bo     = (const float*)d_in[11];
    float* out = (float*)d_out;
    float* ws  = (float*)d_ws;

    float* pe  = ws + WS_PE;
    float* wot = ws + WS_WOT;
    unsigned short* relb = (unsigned short*)(ws + WS_RELB);

    hipLaunchKernelGGL(pe_kernel,   dim3(1024),  dim3(256), 0, stream, pe);
    hipLaunchKernelGGL(rel_kernel,  dim3(16, 8), dim3(256), 0, stream, pe, Wr, relb);
    hipLaunchKernelGGL(wot_kernel,  dim3(256),   dim3(256), 0, stream, Wo, wot);
    hipLaunchKernelGGL(proj_kernel, dim3(512),   dim3(256), 0, stream,
                       query, keys, values, Wq, Wk, Wv, u_bias, v_bias, ws);
    hipLaunchKernelGGL(attn_kernel, dim3(1024),  dim3(512), 0, stream, ws, mask, out);
    hipLaunchKernelGGL(wo_kernel,   dim3(256),   dim3(256), 0, stream, wot, bo, out);
}

// Round 3
// 241.480 us; speedup vs baseline: 9.9255x; 1.5811x over previous
//
#include <hip/hip_runtime.h>
#include <math.h>

// Problem constants
#define NB     16
#define HEADS  8
#define HD     64
#define EMBED  512
#define QL     512
#define KL     512

// ws layout (float-unit offsets)
#define WS_QU   0           // bf16 [16][8][512][64]  (2097152 floats)
#define WS_QV   2097152     // bf16 [16][8][512][64]
#define WS_KB   4194304     // bf16 [16][8][512][64]
#define WS_VT   6291456     // bf16 [16][8][64][512]  (v transposed)
#define WS_PE   8388608     // f32  [1024][512]
#define WS_RELB 8912896     // bf16 [8][1024][64]
#define WS_OH   9175040     // bf16 [16][512][512] (oh staging)
// total 11272192 floats = ~45 MB

typedef __attribute__((ext_vector_type(8))) short bf16x8;
typedef __attribute__((ext_vector_type(4))) float f32x4;
typedef __attribute__((ext_vector_type(8))) unsigned short ushort8v;
typedef __attribute__((ext_vector_type(4))) unsigned short ushort4v;

#define MFMA16 __builtin_amdgcn_mfma_f32_16x16x32_bf16

static __device__ __forceinline__ short f2bf(float x) {
    unsigned u = __builtin_bit_cast(unsigned, x);
    u += 0x7fffu + ((u >> 16) & 1u);      // round-to-nearest-even
    return (short)(u >> 16);
}

// ---------------------------------------------------------------- PE table
__global__ void pe_kernel(float* __restrict__ pe) {
    int j = blockIdx.x;        // 0..1023
    int i = threadIdx.x;       // 0..255
    float invf = exp2f(-(float)i * (13.287712379549449f / 256.0f));
    float ang  = (float)j * invf;
    pe[j * 512 + i]       = sinf(ang);
    pe[j * 512 + 256 + i] = cosf(ang);
}

// ----------------------------------------- rel_b = bf16(PE @ Wr^T) per head
__global__ __launch_bounds__(256) void rel_kernel(const float* __restrict__ pe,
                                                  const float* __restrict__ Wr,
                                                  unsigned short* __restrict__ relb) {
    __shared__ float At[64][68];
    __shared__ float Bt[64][68];
    int j0 = blockIdx.x * 64, e0 = blockIdx.y * 64;
    int tid = threadIdx.x;
    int tj = (tid >> 4) * 4;
    int te = (tid & 15) * 4;
    float acc[4][4] = {};
    for (int f0 = 0; f0 < 512; f0 += 64) {
        for (int i = 0; i < 16; ++i) {
            int idx = tid + 256 * i;
            int r = idx >> 6, c = idx & 63;
            At[r][c] = pe[(j0 + r) * 512 + f0 + c];
            Bt[r][c] = Wr[(e0 + r) * 512 + f0 + c];
        }
        __syncthreads();
        for (int c4 = 0; c4 < 64; c4 += 4) {
            float4 a[4], b[4];
            for (int i = 0; i < 4; ++i) a[i] = *(const float4*)&At[tj + i][c4];
            for (int i = 0; i < 4; ++i) b[i] = *(const float4*)&Bt[te + i][c4];
            for (int i = 0; i < 4; ++i)
                for (int m = 0; m < 4; ++m)
                    acc[i][m] += a[i].x * b[m].x + a[i].y * b[m].y +
                                 a[i].z * b[m].z + a[i].w * b[m].w;
        }
        __syncthreads();
    }
    int e = e0 + te;
    int hh = e >> 6, dd = e & 63;
    for (int i = 0; i < 4; ++i) {
        ushort4v pk;
        for (int m = 0; m < 4; ++m) pk[m] = (unsigned short)f2bf(acc[i][m]);
        *(ushort4v*)&relb[(hh * 1024 + j0 + tj + i) * 64 + dd] = pk;
    }
}

// ------------------------------------------------- q/k/v head projections
__global__ __launch_bounds__(256) void proj_kernel(const float* __restrict__ query,
                                                   const float* __restrict__ keys,
                                                   const float* __restrict__ values,
                                                   const float* __restrict__ Wq,
                                                   const float* __restrict__ Wk,
                                                   const float* __restrict__ Wv,
                                                   const float* __restrict__ u_bias,
                                                   const float* __restrict__ v_bias,
                                                   float* __restrict__ ws) {
    __shared__ float Wl[3][64][68];
    __shared__ float inl[16][512];
    int n  = blockIdx.x >> 5;
    int t0 = (blockIdx.x & 31) * 16;
    int tid = threadIdx.x;
    for (int p = 0; p < 3; ++p) {
        const float* Wp = (p == 0) ? Wq : (p == 1) ? Wk : Wv;
        for (int i = 0; i < 16; ++i) {
            int idx = tid + 256 * i;
            Wl[p][idx >> 6][idx & 63] = Wp[idx];
        }
    }
    int d = tid & 63, h1 = tid >> 6, h2 = h1 + 4;
    unsigned short* qu_b = (unsigned short*)(ws + WS_QU);
    unsigned short* qv_b = (unsigned short*)(ws + WS_QV);
    unsigned short* k_b  = (unsigned short*)(ws + WS_KB);
    unsigned short* vT_b = (unsigned short*)(ws + WS_VT);
    for (int p = 0; p < 3; ++p) {
        const float* src = (p == 0) ? query : (p == 1) ? keys : values;
        __syncthreads();
        for (int i = 0; i < 32; ++i) {
            int idx = tid + 256 * i;
            int r = idx >> 9, c = idx & 511;
            inl[r][c] = src[(n * 512 + t0 + r) * 512 + c];
        }
        __syncthreads();
        float acc1[16] = {}, acc2[16] = {};
        for (int c4 = 0; c4 < 64; c4 += 4) {
            float4 w4 = *(const float4*)&Wl[p][d][c4];
            for (int r = 0; r < 16; ++r) {
                float4 a = *(const float4*)&inl[r][h1 * 64 + c4];
                float4 b = *(const float4*)&inl[r][h2 * 64 + c4];
                acc1[r] += w4.x * a.x + w4.y * a.y + w4.z * a.z + w4.w * a.w;
                acc2[r] += w4.x * b.x + w4.y * b.y + w4.z * b.z + w4.w * b.w;
            }
        }
        if (p == 0) {
            for (int hs = 0; hs < 2; ++hs) {
                int h = hs ? h2 : h1;
                const float* acc = hs ? acc2 : acc1;
                float ub = u_bias[h * 64 + d], vb = v_bias[h * 64 + d];
                int nh = n * 8 + h;
                for (int r = 0; r < 16; ++r) {
                    qu_b[((nh * 512) + t0 + r) * 64 + d] = (unsigned short)f2bf(acc[r] + ub);
                    qv_b[((nh * 512) + t0 + r) * 64 + d] = (unsigned short)f2bf(acc[r] + vb);
                }
            }
        } else if (p == 1) {
            for (int hs = 0; hs < 2; ++hs) {
                int h = hs ? h2 : h1;
                const float* acc = hs ? acc2 : acc1;
                int nh = n * 8 + h;
                for (int r = 0; r < 16; ++r)
                    k_b[((nh * 512) + t0 + r) * 64 + d] = (unsigned short)f2bf(acc[r]);
            }
        } else {
            for (int hs = 0; hs < 2; ++hs) {
                int h = hs ? h2 : h1;
                const float* acc = hs ? acc2 : acc1;
                int nh = n * 8 + h;
                ushort8v p0, p1;
                for (int j = 0; j < 8; ++j) {
                    p0[j] = (unsigned short)f2bf(acc[j]);
                    p1[j] = (unsigned short)f2bf(acc[8 + j]);
                }
                *(ushort8v*)&vT_b[(nh * 64 + d) * 512 + t0]     = p0;
                *(ushort8v*)&vT_b[(nh * 64 + d) * 512 + t0 + 8] = p1;
            }
        }
    }
}

// ------------------------------------------- fused MFMA scores+softmax+PV
// one block per (n, h, q-tile of 64); 512 threads = 8 waves
__global__ __launch_bounds__(512) void attn_kernel(float* __restrict__ ws,
                                                   const int* __restrict__ mask,
                                                   float* __restrict__ d_out) {
    __shared__ __align__(16) float S[64][516];              // 132096 B
    __shared__ __align__(16) unsigned short stage[128][64]; // 16384 B

    const unsigned short* qu_b = (const unsigned short*)(ws + WS_QU);
    const unsigned short* qv_b = (const unsigned short*)(ws + WS_QV);
    const unsigned short* k_b  = (const unsigned short*)(ws + WS_KB);
    const unsigned short* vT_b = (const unsigned short*)(ws + WS_VT);
    const unsigned short* relb = (const unsigned short*)(ws + WS_RELB);
    unsigned short* ohb = (unsigned short*)(ws + WS_OH);     // bf16 oh staging
    float* attn = d_out + 4194304;       // [N][H][Q][K]

    int blk = blockIdx.x;
    int n  = blk >> 6;
    int h  = (blk >> 3) & 7;
    int q0 = (blk & 7) * 64;
    int nh = n * 8 + h;

    int tid  = threadIdx.x;
    int w    = tid >> 6, lane = tid & 63;
    int wq   = w >> 1, half = w & 1;
    int fr   = lane & 15, fg = lane >> 4;

    // ---- stage qu (rows 0-63) + qv (rows 64-127), hoist q fragments to regs
    for (int p = 0; p < 2; ++p) {
        int idx = tid + 512 * p;
        int row = idx >> 3, slot = idx & 7;
        const unsigned short* g = (row < 64)
            ? &qu_b[((nh * 512) + q0 + row) * 64 + slot * 8]
            : &qv_b[((nh * 512) + q0 + row - 64) * 64 + slot * 8];
        *(bf16x8*)&stage[row][((slot ^ (row & 7))) * 8] = *(const bf16x8*)g;
    }
    __syncthreads();
    bf16x8 qu_f[2], qv_f[2];
    {
        int ar = wq * 16 + fr;
#pragma unroll
        for (int s = 0; s < 2; ++s) {
            int sl = ((fg + s * 4) ^ (ar & 7)) * 8;
            qu_f[s] = *(const bf16x8*)&stage[ar][sl];
            qv_f[s] = *(const bf16x8*)&stage[64 + ar][sl];
        }
    }

    // ---- content scores: S[q][k] = (q+u) . k
    for (int kc = 0; kc < 4; ++kc) {
        int k0 = kc * 128;
        __syncthreads();
        for (int p = 0; p < 2; ++p) {
            int idx = tid + 512 * p;
            int row = idx >> 3, slot = idx & 7;
            const unsigned short* g = &k_b[((nh * 512) + k0 + row) * 64 + slot * 8];
            *(bf16x8*)&stage[row][((slot ^ (row & 7))) * 8] = *(const bf16x8*)g;
        }
        __syncthreads();
#pragma unroll
        for (int t = 0; t < 4; ++t) {
            f32x4 acc = {0.f, 0.f, 0.f, 0.f};
            int br = half * 64 + t * 16 + fr;
#pragma unroll
            for (int s = 0; s < 2; ++s) {
                bf16x8 bf = *(const bf16x8*)&stage[br][((fg + s * 4) ^ (br & 7)) * 8];
                acc = MFMA16(qu_f[s], bf, acc, 0, 0, 0);
            }
            int cc = k0 + br;
            int rb = wq * 16 + fg * 4;
#pragma unroll
            for (int i = 0; i < 4; ++i) S[rb + i][cc] = acc[i];
        }
    }

    // ---- position scores: S[r][k] += (q+v) . rel[j],  k = r + 511 - jj
    for (int jc = 0; jc < 5; ++jc) {
        __syncthreads();
        for (int p = 0; p < 2; ++p) {
            int idx = tid + 512 * p;
            int row = idx >> 3, slot = idx & 7;
            int j = q0 + 1 + jc * 128 + row;
            if (j > 1023) j = 1023;
            const unsigned short* g = &relb[(h * 1024 + j) * 64 + slot * 8];
            *(bf16x8*)&stage[row][((slot ^ (row & 7))) * 8] = *(const bf16x8*)g;
        }
        __syncthreads();
#pragma unroll
        for (int t = 0; t < 4; ++t) {
            f32x4 acc = {0.f, 0.f, 0.f, 0.f};
            int br = half * 64 + t * 16 + fr;
#pragma unroll
            for (int s = 0; s < 2; ++s) {
                bf16x8 bf = *(const bf16x8*)&stage[br][((fg + s * 4) ^ (br & 7)) * 8];
                acc = MFMA16(qv_f[s], bf, acc, 0, 0, 0);
            }
            int jj = jc * 128 + br;
#pragma unroll
            for (int i = 0; i < 4; ++i) {
                int r = wq * 16 + fg * 4 + i;
                int k = r + 511 - jj;
                if ((unsigned)k < 512u) S[r][k] += acc[i];
            }
        }
    }

    // ---- mask + scale + softmax; write attn; leave P (f32) in S
    __syncthreads();
    for (int rr = 0; rr < 8; ++rr) {
        int r = w * 8 + rr;
        const int* mrow = mask + ((long)(n * 512 + q0 + r)) * 512;
        float lg[8];
        float mx = -3.0e38f;
#pragma unroll
        for (int j = 0; j < 8; ++j) {
            int k = lane + 64 * j;
            float s = S[r][k];
            int m = mrow[k];
            float l = (m == 0) ? -1.25e19f : s * 0.125f;
            lg[j] = l;
            mx = fmaxf(mx, l);
        }
        for (int o = 32; o > 0; o >>= 1) mx = fmaxf(mx, __shfl_xor(mx, o, 64));
        float sum = 0.f;
#pragma unroll
        for (int j = 0; j < 8; ++j) { lg[j] = __expf(lg[j] - mx); sum += lg[j]; }
        for (int o = 32; o > 0; o >>= 1) sum += __shfl_xor(sum, o, 64);
        float inv = 1.0f / sum;
        float* arow = attn + ((long)(nh * 512 + q0 + r)) * 512;
#pragma unroll
        for (int j = 0; j < 8; ++j) {
            int k = lane + 64 * j;
            float p = lg[j] * inv;
            S[r][k] = p;
            arow[k] = p;
        }
    }

    // ---- PV: oh[q][d] = P . v   (vT staged, P converted bf16 from S)
    f32x4 oacc[2] = {{0.f,0.f,0.f,0.f},{0.f,0.f,0.f,0.f}};
    for (int kc = 0; kc < 4; ++kc) {
        int k0 = kc * 128;
        __syncthreads();
        for (int p = 0; p < 2; ++p) {
            int idx = tid + 512 * p;
            int row = idx >> 3, slot = idx & 7;
            int dd = row & 63;
            int koff = (row >> 6) * 64 + slot * 8;
            const unsigned short* g = &vT_b[(nh * 64 + dd) * 512 + k0 + koff];
            *(bf16x8*)&stage[row][((slot ^ (row & 7))) * 8] = *(const bf16x8*)g;
        }
        __syncthreads();
#pragma unroll
        for (int sub = 0; sub < 2; ++sub) {
            bf16x8 pf[2];
#pragma unroll
            for (int s = 0; s < 2; ++s) {
                const float* sp = &S[wq * 16 + fr][k0 + sub * 64 + s * 32 + fg * 8];
                f32x4 a = *(const f32x4*)sp;
                f32x4 b = *(const f32x4*)(sp + 4);
                bf16x8 pk;
                pk[0] = f2bf(a.x); pk[1] = f2bf(a.y); pk[2] = f2bf(a.z); pk[3] = f2bf(a.w);
                pk[4] = f2bf(b.x); pk[5] = f2bf(b.y); pk[6] = f2bf(b.z); pk[7] = f2bf(b.w);
                pf[s] = pk;
            }
#pragma unroll
            for (int t = 0; t < 2; ++t) {
                int br = sub * 64 + half * 32 + t * 16 + fr;
#pragma unroll
                for (int s = 0; s < 2; ++s) {
                    bf16x8 bf = *(const bf16x8*)&stage[br][((fg + s * 4) ^ (br & 7)) * 8];
                    oacc[t] = MFMA16(pf[s], bf, oacc[t], 0, 0, 0);
                }
            }
        }
    }
#pragma unroll
    for (int t = 0; t < 2; ++t)
#pragma unroll
        for (int i = 0; i < 4; ++i)
            ohb[((long)(n * 512 + q0 + wq * 16 + fg * 4 + i)) * 512 +
                h * 64 + half * 32 + t * 16 + fr] = (unsigned short)f2bf(oacc[t][i]);
}

// ----------------------- out = oh @ Wo^T + bo  (bf16 MFMA, f32 epilogue)
// grid 512: bm = blk>>3 (128-row tile of 8192), bn = blk&7 (64-col tile)
__global__ __launch_bounds__(256) void wo_kernel(const float* __restrict__ ws,
                                                 const float* __restrict__ Wo,
                                                 const float* __restrict__ bo,
                                                 float* __restrict__ d_out) {
    __shared__ __align__(16) unsigned short At[128][64];   // 16 KB
    __shared__ __align__(16) unsigned short Bt[64][64];    // 8 KB
    const unsigned short* ohb = (const unsigned short*)(ws + WS_OH);
    int bm = blockIdx.x >> 3, bn = blockIdx.x & 7;
    int tid = threadIdx.x;
    int w = tid >> 6, lane = tid & 63;
    int fr = lane & 15, fg = lane >> 4;
    f32x4 acc[2][4] = {};
    for (int kk = 0; kk < 512; kk += 64) {
        __syncthreads();
        for (int p = 0; p < 4; ++p) {
            int idx = tid + 256 * p;       // 0..1023
            int row = idx >> 3, slot = idx & 7;
            *(bf16x8*)&At[row][((slot ^ (row & 7))) * 8] =
                *(const bf16x8*)&ohb[(long)(bm * 128 + row) * 512 + kk + slot * 8];
        }
        for (int p = 0; p < 2; ++p) {
            int idx = tid + 256 * p;       // 0..511
            int row = idx >> 3, slot = idx & 7;
            const float* g = &Wo[(bn * 64 + row) * 512 + kk + slot * 8];
            float4 a = *(const float4*)g;
            float4 b = *(const float4*)(g + 4);
            ushort8v pk;
            pk[0] = f2bf(a.x); pk[1] = f2bf(a.y); pk[2] = f2bf(a.z); pk[3] = f2bf(a.w);
            pk[4] = f2bf(b.x); pk[5] = f2bf(b.y); pk[6] = f2bf(b.z); pk[7] = f2bf(b.w);
            *(ushort8v*)&Bt[row][((slot ^ (row & 7))) * 8] = pk;
        }
        __syncthreads();
        bf16x8 af[2][2], bfr[4][2];
#pragma unroll
        for (int t = 0; t < 2; ++t) {
            int ar = w * 32 + t * 16 + fr;
#pragma unroll
            for (int s = 0; s < 2; ++s)
                af[t][s] = *(const bf16x8*)&At[ar][((fg + s * 4) ^ (ar & 7)) * 8];
        }
#pragma unroll
        for (int c = 0; c < 4; ++c) {
            int br = c * 16 + fr;
#pragma unroll
            for (int s = 0; s < 2; ++s)
                bfr[c][s] = *(const bf16x8*)&Bt[br][((fg + s * 4) ^ (br & 7)) * 8];
        }
#pragma unroll
        for (int t = 0; t < 2; ++t)
#pragma unroll
            for (int c = 0; c < 4; ++c)
#pragma unroll
                for (int s = 0; s < 2; ++s)
                    acc[t][c] = MFMA16(af[t][s], bfr[c][s], acc[t][c], 0, 0, 0);
    }
#pragma unroll
    for (int t = 0; t < 2; ++t)
#pragma unroll
        for (int c = 0; c < 4; ++c) {
            int col = bn * 64 + c * 16 + fr;
            float b = bo[col];
#pragma unroll
            for (int i = 0; i < 4; ++i) {
                int row = bm * 128 + w * 32 + t * 16 + fg * 4 + i;
                d_out[(long)row * 512 + col] = acc[t][c][i] + b;
            }
        }
}

extern "C" void kernel_launch(void* const* d_in, const int* in_sizes, int n_in,
                              void* d_out, int out_size, void* d_ws, size_t ws_size,
                              hipStream_t stream) {
    const float* values = (const float*)d_in[0];
    const float* keys   = (const float*)d_in[1];
    const float* query  = (const float*)d_in[2];
    const int*   mask   = (const int*)d_in[3];
    const float* Wv     = (const float*)d_in[4];
    const float* Wk     = (const float*)d_in[5];
    const float* Wq     = (const float*)d_in[6];
    const float* Wr     = (const float*)d_in[7];
    const float* u_bias = (const float*)d_in[8];
    const float* v_bias = (const float*)d_in[9];
    const float* Wo     = (const float*)d_in[10];
    const float* bo     = (const float*)d_in[11];
    float* out = (float*)d_out;
    float* ws  = (float*)d_ws;

    float* pe  = ws + WS_PE;
    unsigned short* relb = (unsigned short*)(ws + WS_RELB);

    hipLaunchKernelGGL(pe_kernel,   dim3(1024),  dim3(256), 0, stream, pe);
    hipLaunchKernelGGL(rel_kernel,  dim3(16, 8), dim3(256), 0, stream, pe, Wr, relb);
    hipLaunchKernelGGL(proj_kernel, dim3(512),   dim3(256), 0, stream,
                       query, keys, values, Wq, Wk, Wv, u_bias, v_bias, ws);
    hipLaunchKernelGGL(attn_kernel, dim3(1024),  dim3(512), 0, stream, ws, mask, out);
    hipLaunchKernelGGL(wo_kernel,   dim3(512),   dim3(256), 0, stream, ws, Wo, bo, out);
}

// Round 4
// 190.623 us; speedup vs baseline: 12.5736x; 1.2668x over previous
//
#include <hip/hip_runtime.h>
#include <math.h>

// Problem constants
#define NB     16
#define HEADS  8
#define HD     64
#define EMBED  512
#define QL     512
#define KL     512

// ws layout (float-unit offsets)
#define WS_QU   0           // bf16 [16][8][512][64]
#define WS_QV   2097152     // bf16 [16][8][512][64]
#define WS_KB   4194304     // bf16 [16][8][512][64]
#define WS_VT   6291456     // bf16 [16][8][64][512]  (v transposed)
#define WS_PEB  8388608     // bf16 [1024][512]
#define WS_RELB 8912896     // bf16 [8][1024][64]
#define WS_OH   9175040     // bf16 [16][512][512]

typedef __attribute__((ext_vector_type(8))) short bf16x8;
typedef __attribute__((ext_vector_type(4))) float f32x4;
typedef __attribute__((ext_vector_type(8))) unsigned short ushort8v;
typedef __attribute__((ext_vector_type(4))) unsigned short ushort4v;

#define MFMA16 __builtin_amdgcn_mfma_f32_16x16x32_bf16

static __device__ __forceinline__ unsigned short f2bf(float x) {
    unsigned u = __builtin_bit_cast(unsigned, x);
    u += 0x7fffu + ((u >> 16) & 1u);      // round-to-nearest-even
    return (unsigned short)(u >> 16);
}

// ---------------------------------------------------------------- PE table (bf16)
__global__ void pe_kernel(unsigned short* __restrict__ peb) {
    int j = blockIdx.x;        // 0..1023
    int i = threadIdx.x;       // 0..255
    float invf = exp2f(-(float)i * (13.287712379549449f / 256.0f));
    float ang  = (float)j * invf;
    peb[j * 512 + i]       = f2bf(sinf(ang));
    peb[j * 512 + 256 + i] = f2bf(cosf(ang));
}

// ----------------------------------------- relb = bf16(PE @ Wr^T), MFMA
// grid 128: bm = blk>>3 (64-row j tile), bn = blk&7 (64-col e tile = head bn)
__global__ __launch_bounds__(256) void rel_kernel(const unsigned short* __restrict__ peb,
                                                  const float* __restrict__ Wr,
                                                  unsigned short* __restrict__ relb) {
    __shared__ __align__(16) unsigned short At[64][64];
    __shared__ __align__(16) unsigned short Bt[64][64];
    int bm = blockIdx.x >> 3, bn = blockIdx.x & 7;
    int tid = threadIdx.x;
    int w = tid >> 6, lane = tid & 63;
    int fr = lane & 15, fg = lane >> 4;
    f32x4 acc[4] = {};
    for (int kk = 0; kk < 512; kk += 64) {
        __syncthreads();
        for (int p = 0; p < 2; ++p) {
            int idx = tid + 256 * p;              // 0..511
            int row = idx >> 3, slot = idx & 7;
            *(bf16x8*)&At[row][((slot ^ (row & 7))) * 8] =
                *(const bf16x8*)&peb[(bm * 64 + row) * 512 + kk + slot * 8];
        }
        for (int p = 0; p < 4; ++p) {
            int idx = tid + 256 * p;              // 0..1023 = 64 rows x 16 float4
            int row = idx >> 4, c4 = idx & 15;
            float4 v = *(const float4*)&Wr[(bn * 64 + row) * 512 + kk + c4 * 4];
            ushort4v pk;
            pk[0] = f2bf(v.x); pk[1] = f2bf(v.y); pk[2] = f2bf(v.z); pk[3] = f2bf(v.w);
            int slot = c4 >> 1, rem = (c4 & 1) * 4;
            *(ushort4v*)&Bt[row][((slot ^ (row & 7))) * 8 + rem] = pk;
        }
        __syncthreads();
        bf16x8 af[2];
        int ar = w * 16 + fr;
#pragma unroll
        for (int s = 0; s < 2; ++s)
            af[s] = *(const bf16x8*)&At[ar][((fg + 4 * s) ^ (ar & 7)) * 8];
#pragma unroll
        for (int c = 0; c < 4; ++c) {
            int br = c * 16 + fr;
#pragma unroll
            for (int s = 0; s < 2; ++s) {
                bf16x8 bf = *(const bf16x8*)&Bt[br][((fg + 4 * s) ^ (br & 7)) * 8];
                acc[c] = MFMA16(af[s], bf, acc[c], 0, 0, 0);
            }
        }
    }
#pragma unroll
    for (int c = 0; c < 4; ++c)
#pragma unroll
        for (int i = 0; i < 4; ++i)
            relb[(bn * 1024 + bm * 64 + w * 16 + fg * 4 + i) * 64 + c * 16 + fr] =
                f2bf(acc[c][i]);
}

// ------------------------------------------------- q/k/v head projections, MFMA
// grid 256: n = blk>>4, t0 = (blk&15)*32; 256 threads = 4 waves; wave w -> heads 2w,2w+1
__global__ __launch_bounds__(256) void proj_kernel(const float* __restrict__ query,
                                                   const float* __restrict__ keys,
                                                   const float* __restrict__ values,
                                                   const float* __restrict__ Wq,
                                                   const float* __restrict__ Wk,
                                                   const float* __restrict__ Wv,
                                                   const float* __restrict__ u_bias,
                                                   const float* __restrict__ v_bias,
                                                   float* __restrict__ ws) {
    __shared__ __align__(16) unsigned short inb[32][512];     // 32 KB
    __shared__ __align__(16) unsigned short Wb[3][64][64];    // 24 KB
    __shared__ __align__(16) unsigned short vtile[4][64][36]; // 18 KB
    int n = blockIdx.x >> 4, t0 = (blockIdx.x & 15) * 32;
    int tid = threadIdx.x;
    int w = tid >> 6, lane = tid & 63;
    int fr = lane & 15, fg = lane >> 4;

    for (int p = 0; p < 3; ++p) {
        const float* Wp = (p == 0) ? Wq : (p == 1) ? Wk : Wv;
        for (int it = 0; it < 4; ++it) {
            int idx = tid + 256 * it;            // 0..1023 = 64 rows x 16 float4
            int row = idx >> 4, c4 = idx & 15;
            float4 v = *(const float4*)&Wp[row * 64 + c4 * 4];
            ushort4v pk;
            pk[0] = f2bf(v.x); pk[1] = f2bf(v.y); pk[2] = f2bf(v.z); pk[3] = f2bf(v.w);
            int slot = c4 >> 1, rem = (c4 & 1) * 4;
            *(ushort4v*)&Wb[p][row][((slot ^ (row & 7))) * 8 + rem] = pk;
        }
    }
    unsigned short* qu_b = (unsigned short*)(ws + WS_QU);
    unsigned short* qv_b = (unsigned short*)(ws + WS_QV);
    unsigned short* k_b  = (unsigned short*)(ws + WS_KB);
    unsigned short* vT_b = (unsigned short*)(ws + WS_VT);

    for (int p = 0; p < 3; ++p) {
        const float* src = (p == 0) ? query : (p == 1) ? keys : values;
        __syncthreads();                         // Wb ready / inb WAR
        for (int it = 0; it < 16; ++it) {
            int idx = tid + 256 * it;            // 0..4095 = 32 rows x 128 float4
            int row = idx >> 7, c4 = idx & 127;
            float4 v = *(const float4*)&src[((long)(n * 512 + t0 + row)) * 512 + c4 * 4];
            ushort4v pk;
            pk[0] = f2bf(v.x); pk[1] = f2bf(v.y); pk[2] = f2bf(v.z); pk[3] = f2bf(v.w);
            int slot = c4 >> 1, rem = (c4 & 1) * 4;
            *(ushort4v*)&inb[row][((slot ^ (row & 7))) * 8 + rem] = pk;
        }
        __syncthreads();
        for (int hh = 0; hh < 2; ++hh) {
            int h = w * 2 + hh, nh = n * 8 + h;
            bf16x8 af[2][2];
#pragma unroll
            for (int tt = 0; tt < 2; ++tt) {
                int ar = tt * 16 + fr;
#pragma unroll
                for (int s = 0; s < 2; ++s)
                    af[tt][s] = *(const bf16x8*)&inb[ar][(h * 8 + ((fg + 4 * s) ^ (ar & 7))) * 8];
            }
            f32x4 acc[2][4] = {};
#pragma unroll
            for (int dt = 0; dt < 4; ++dt) {
                int br = dt * 16 + fr;
                bf16x8 bf[2];
#pragma unroll
                for (int s = 0; s < 2; ++s)
                    bf[s] = *(const bf16x8*)&Wb[p][br][((fg + 4 * s) ^ (br & 7)) * 8];
#pragma unroll
                for (int tt = 0; tt < 2; ++tt)
#pragma unroll
                    for (int s = 0; s < 2; ++s)
                        acc[tt][dt] = MFMA16(af[tt][s], bf[s], acc[tt][dt], 0, 0, 0);
            }
            if (p == 0) {
#pragma unroll
                for (int dt = 0; dt < 4; ++dt) {
                    float ub = u_bias[h * 64 + dt * 16 + fr];
                    float vb = v_bias[h * 64 + dt * 16 + fr];
#pragma unroll
                    for (int tt = 0; tt < 2; ++tt)
#pragma unroll
                        for (int i = 0; i < 4; ++i) {
                            long o = ((long)(nh * 512 + t0 + tt * 16 + fg * 4 + i)) * 64 +
                                     dt * 16 + fr;
                            qu_b[o] = f2bf(acc[tt][dt][i] + ub);
                            qv_b[o] = f2bf(acc[tt][dt][i] + vb);
                        }
                }
            } else if (p == 1) {
#pragma unroll
                for (int dt = 0; dt < 4; ++dt)
#pragma unroll
                    for (int tt = 0; tt < 2; ++tt)
#pragma unroll
                        for (int i = 0; i < 4; ++i)
                            k_b[((long)(nh * 512 + t0 + tt * 16 + fg * 4 + i)) * 64 +
                                dt * 16 + fr] = f2bf(acc[tt][dt][i]);
            } else {
                // transpose via per-wave LDS tile, then coalesced vT store
#pragma unroll
                for (int dt = 0; dt < 4; ++dt)
#pragma unroll
                    for (int tt = 0; tt < 2; ++tt)
#pragma unroll
                        for (int i = 0; i < 4; ++i)
                            vtile[w][dt * 16 + fr][tt * 16 + fg * 4 + i] =
                                f2bf(acc[tt][dt][i]);
                __syncthreads();
#pragma unroll
                for (int dg = 0; dg < 8; ++dg) {
                    int d = dg * 8 + (lane >> 3), tq = lane & 7;
                    *(ushort4v*)&vT_b[((long)(nh * 64 + d)) * 512 + t0 + tq * 4] =
                        *(const ushort4v*)&vtile[w][d][tq * 4];
                }
                __syncthreads();
            }
        }
    }
}

// ------------------------------------------- fused MFMA scores+softmax+PV
// one block per (n, h, q-tile of 32); 256 threads = 4 waves; B-operands direct from L2
__global__ __launch_bounds__(256) void attn_kernel(float* __restrict__ ws,
                                                   const int* __restrict__ mask,
                                                   float* __restrict__ d_out) {
    __shared__ __align__(16) float S[32][516];   // 66048 B -> 2 blocks/CU

    const unsigned short* qu_b = (const unsigned short*)(ws + WS_QU);
    const unsigned short* qv_b = (const unsigned short*)(ws + WS_QV);
    const unsigned short* k_b  = (const unsigned short*)(ws + WS_KB);
    const unsigned short* vT_b = (const unsigned short*)(ws + WS_VT);
    const unsigned short* relb = (const unsigned short*)(ws + WS_RELB);
    unsigned short* ohb = (unsigned short*)(ws + WS_OH);
    float* attn = d_out + 4194304;               // [N][H][Q][K]

    int blk = blockIdx.x;
    int n  = blk >> 7;
    int h  = (blk >> 4) & 7;
    int q0 = (blk & 15) * 32;
    int nh = n * 8 + h;

    int tid  = threadIdx.x;
    int w    = tid >> 6, lane = tid & 63;
    int wq   = w & 1, half = w >> 1;
    int fr   = lane & 15, fg = lane >> 4;

    // q fragments (direct load, no staging)
    bf16x8 quf[2], qvf[2];
    {
        long qb = ((long)(nh * 512 + q0 + wq * 16 + fr)) * 64;
#pragma unroll
        for (int s = 0; s < 2; ++s) {
            quf[s] = *(const bf16x8*)&qu_b[qb + (fg + 4 * s) * 8];
            qvf[s] = *(const bf16x8*)&qv_b[qb + (fg + 4 * s) * 8];
        }
    }

    // ---- content: S[r][k] = (q+u).k ; wave covers k in [half*256, half*256+256)
    const unsigned short* kbase = k_b + (long)nh * 512 * 64;
    for (int kc = 0; kc < 4; ++kc) {
#pragma unroll
        for (int t = 0; t < 4; ++t) {
            int kcol = half * 256 + kc * 64 + t * 16 + fr;
            const unsigned short* kp = kbase + (long)kcol * 64;
            bf16x8 b0 = *(const bf16x8*)&kp[fg * 8];
            bf16x8 b1 = *(const bf16x8*)&kp[(fg + 4) * 8];
            f32x4 acc = {0.f, 0.f, 0.f, 0.f};
            acc = MFMA16(quf[0], b0, acc, 0, 0, 0);
            acc = MFMA16(quf[1], b1, acc, 0, 0, 0);
            int rb = wq * 16 + fg * 4;
#pragma unroll
            for (int i = 0; i < 4; ++i) S[rb + i][kcol] = acc[i];
        }
    }
    __syncthreads();

    // ---- position: S[r][k] += (q+v).rel[j], k = r + 511 - jj
    // wave covers jj in [half*288, half*288+288); disjoint k-ranges per half -> no race
    const unsigned short* rbase = relb + (long)h * 1024 * 64;
    for (int jt = 0; jt < 18; ++jt) {
        int jj = half * 288 + jt * 16 + fr;
        int j = q0 + 1 + jj; if (j > 1023) j = 1023;   // clamped rows target k<0, discarded
        const unsigned short* rp = rbase + (long)j * 64;
        bf16x8 b0 = *(const bf16x8*)&rp[fg * 8];
        bf16x8 b1 = *(const bf16x8*)&rp[(fg + 4) * 8];
        f32x4 acc = {0.f, 0.f, 0.f, 0.f};
        acc = MFMA16(qvf[0], b0, acc, 0, 0, 0);
        acc = MFMA16(qvf[1], b1, acc, 0, 0, 0);
#pragma unroll
        for (int i = 0; i < 4; ++i) {
            int r = wq * 16 + fg * 4 + i;
            int k = r + 511 - jj;
            if ((unsigned)k < 512u) S[r][k] += acc[i];
        }
    }
    __syncthreads();

    // ---- mask + scale + softmax; write attn; leave P (f32) in S
    for (int rr = 0; rr < 8; ++rr) {
        int r = w * 8 + rr;
        const int* mrow = mask + ((long)(n * 512 + q0 + r)) * 512;
        float lg[8];
        float mx = -3.0e38f;
#pragma unroll
        for (int j = 0; j < 8; ++j) {
            int k = lane + 64 * j;
            float s = S[r][k];
            int m = mrow[k];
            float l = (m == 0) ? -1.25e19f : s * 0.125f;
            lg[j] = l;
            mx = fmaxf(mx, l);
        }
        for (int o = 32; o > 0; o >>= 1) mx = fmaxf(mx, __shfl_xor(mx, o, 64));
        float sum = 0.f;
#pragma unroll
        for (int j = 0; j < 8; ++j) { lg[j] = __expf(lg[j] - mx); sum += lg[j]; }
        for (int o = 32; o > 0; o >>= 1) sum += __shfl_xor(sum, o, 64);
        float inv = 1.0f / sum;
        float* arow = attn + ((long)(nh * 512 + q0 + r)) * 512;
#pragma unroll
        for (int j = 0; j < 8; ++j) {
            int k = lane + 64 * j;
            float p = lg[j] * inv;
            S[r][k] = p;
            arow[k] = p;
        }
    }
    __syncthreads();

    // ---- PV: oh[q][d] = P.v ; wave -> q-tile wq, d in [half*32, half*32+32)
    f32x4 oacc[2] = {{0.f,0.f,0.f,0.f},{0.f,0.f,0.f,0.f}};
    const unsigned short* vbase = vT_b + (long)nh * 64 * 512;
    for (int kk = 0; kk < 8; ++kk) {
        bf16x8 pf[2];
#pragma unroll
        for (int s = 0; s < 2; ++s) {
            const float* sp = &S[wq * 16 + fr][kk * 64 + s * 32 + fg * 8];
            f32x4 a = *(const f32x4*)sp;
            f32x4 b = *(const f32x4*)(sp + 4);
            bf16x8 pk;
            pk[0] = f2bf(a.x); pk[1] = f2bf(a.y); pk[2] = f2bf(a.z); pk[3] = f2bf(a.w);
            pk[4] = f2bf(b.x); pk[5] = f2bf(b.y); pk[6] = f2bf(b.z); pk[7] = f2bf(b.w);
            pf[s] = pk;
        }
#pragma unroll
        for (int t = 0; t < 2; ++t) {
            int d = half * 32 + t * 16 + fr;
            const unsigned short* vp = vbase + (long)d * 512 + kk * 64;
#pragma unroll
            for (int s = 0; s < 2; ++s) {
                bf16x8 bf = *(const bf16x8*)&vp[(fg + 4 * s) * 8];
                oacc[t] = MFMA16(pf[s], bf, oacc[t], 0, 0, 0);
            }
        }
    }
#pragma unroll
    for (int t = 0; t < 2; ++t)
#pragma unroll
        for (int i = 0; i < 4; ++i)
            ohb[((long)(n * 512 + q0 + wq * 16 + fg * 4 + i)) * 512 +
                h * 64 + half * 32 + t * 16 + fr] = f2bf(oacc[t][i]);
}

// ----------------------- out = oh @ Wo^T + bo  (bf16 MFMA, f32 epilogue)
__global__ __launch_bounds__(256) void wo_kernel(const float* __restrict__ ws,
                                                 const float* __restrict__ Wo,
                                                 const float* __restrict__ bo,
                                                 float* __restrict__ d_out) {
    __shared__ __align__(16) unsigned short At[128][64];   // 16 KB
    __shared__ __align__(16) unsigned short Bt[64][64];    // 8 KB
    const unsigned short* ohb = (const unsigned short*)(ws + WS_OH);
    int bm = blockIdx.x >> 3, bn = blockIdx.x & 7;
    int tid = threadIdx.x;
    int w = tid >> 6, lane = tid & 63;
    int fr = lane & 15, fg = lane >> 4;
    f32x4 acc[2][4] = {};
    for (int kk = 0; kk < 512; kk += 64) {
        __syncthreads();
        for (int p = 0; p < 4; ++p) {
            int idx = tid + 256 * p;       // 0..1023
            int row = idx >> 3, slot = idx & 7;
            *(bf16x8*)&At[row][((slot ^ (row & 7))) * 8] =
                *(const bf16x8*)&ohb[(long)(bm * 128 + row) * 512 + kk + slot * 8];
        }
        for (int p = 0; p < 2; ++p) {
            int idx = tid + 256 * p;       // 0..511
            int row = idx >> 3, slot = idx & 7;
            const float* g = &Wo[(bn * 64 + row) * 512 + kk + slot * 8];
            float4 a = *(const float4*)g;
            float4 b = *(const float4*)(g + 4);
            ushort8v pk;
            pk[0] = f2bf(a.x); pk[1] = f2bf(a.y); pk[2] = f2bf(a.z); pk[3] = f2bf(a.w);
            pk[4] = f2bf(b.x); pk[5] = f2bf(b.y); pk[6] = f2bf(b.z); pk[7] = f2bf(b.w);
            *(ushort8v*)&Bt[row][((slot ^ (row & 7))) * 8] = pk;
        }
        __syncthreads();
        bf16x8 af[2][2], bfr[4][2];
#pragma unroll
        for (int t = 0; t < 2; ++t) {
            int ar = w * 32 + t * 16 + fr;
#pragma unroll
            for (int s = 0; s < 2; ++s)
                af[t][s] = *(const bf16x8*)&At[ar][((fg + s * 4) ^ (ar & 7)) * 8];
        }
#pragma unroll
        for (int c = 0; c < 4; ++c) {
            int br = c * 16 + fr;
#pragma unroll
            for (int s = 0; s < 2; ++s)
                bfr[c][s] = *(const bf16x8*)&Bt[br][((fg + s * 4) ^ (br & 7)) * 8];
        }
#pragma unroll
        for (int t = 0; t < 2; ++t)
#pragma unroll
            for (int c = 0; c < 4; ++c)
#pragma unroll
                for (int s = 0; s < 2; ++s)
                    acc[t][c] = MFMA16(af[t][s], bfr[c][s], acc[t][c], 0, 0, 0);
    }
#pragma unroll
    for (int t = 0; t < 2; ++t)
#pragma unroll
        for (int c = 0; c < 4; ++c) {
            int col = bn * 64 + c * 16 + fr;
            float b = bo[col];
#pragma unroll
            for (int i = 0; i < 4; ++i) {
                int row = bm * 128 + w * 32 + t * 16 + fg * 4 + i;
                d_out[(long)row * 512 + col] = acc[t][c][i] + b;
            }
        }
}

extern "C" void kernel_launch(void* const* d_in, const int* in_sizes, int n_in,
                              void* d_out, int out_size, void* d_ws, size_t ws_size,
                              hipStream_t stream) {
    const float* values = (const float*)d_in[0];
    const float* keys   = (const float*)d_in[1];
    const float* query  = (const float*)d_in[2];
    const int*   mask   = (const int*)d_in[3];
    const float* Wv     = (const float*)d_in[4];
    const float* Wk     = (const float*)d_in[5];
    const float* Wq     = (const float*)d_in[6];
    const float* Wr     = (const float*)d_in[7];
    const float* u_bias = (const float*)d_in[8];
    const float* v_bias = (const float*)d_in[9];
    const float* Wo     = (const float*)d_in[10];
    const float* bo     = (const float*)d_in[11];
    float* out = (float*)d_out;
    float* ws  = (float*)d_ws;

    unsigned short* peb  = (unsigned short*)(ws + WS_PEB);
    unsigned short* relb = (unsigned short*)(ws + WS_RELB);

    hipLaunchKernelGGL(pe_kernel,   dim3(1024),  dim3(256), 0, stream, peb);
    hipLaunchKernelGGL(rel_kernel,  dim3(128),   dim3(256), 0, stream, peb, Wr, relb);
    hipLaunchKernelGGL(proj_kernel, dim3(256),   dim3(256), 0, stream,
                       query, keys, values, Wq, Wk, Wv, u_bias, v_bias, ws);
    hipLaunchKernelGGL(attn_kernel, dim3(2048),  dim3(256), 0, stream, ws, mask, out);
    hipLaunchKernelGGL(wo_kernel,   dim3(512),   dim3(256), 0, stream, ws, Wo, bo, out);
}

// Round 5
// 147.181 us; speedup vs baseline: 16.2848x; 1.2952x over previous
//
#include <hip/hip_runtime.h>
#include <math.h>

// Problem constants
#define NB     16
#define HEADS  8
#define HD     64
#define EMBED  512
#define QL     512
#define KL     512

// ws layout (float-unit offsets)
#define WS_QU   0           // bf16 [16][8][512][64]
#define WS_QV   2097152     // bf16 [16][8][512][64]
#define WS_KB   4194304     // bf16 [16][8][512][64]
#define WS_VT   6291456     // bf16 [16][8][64][512]  (v transposed)
#define WS_PEB  8388608     // bf16 [1024][512]
#define WS_RELB 8912896     // bf16 [8][1024][64]
#define WS_OH   9175040     // bf16 [16][512][512]

typedef __attribute__((ext_vector_type(8))) short bf16x8;
typedef __attribute__((ext_vector_type(4))) float f32x4;
typedef __attribute__((ext_vector_type(8))) unsigned short ushort8v;
typedef __attribute__((ext_vector_type(4))) unsigned short ushort4v;

#define MFMA16 __builtin_amdgcn_mfma_f32_16x16x32_bf16

static __device__ __forceinline__ unsigned short f2bf(float x) {
    unsigned u = __builtin_bit_cast(unsigned, x);
    u += 0x7fffu + ((u >> 16) & 1u);      // round-to-nearest-even
    return (unsigned short)(u >> 16);
}

// ---------------------------------------------------------------- PE table (bf16)
__global__ void pe_kernel(unsigned short* __restrict__ peb) {
    int j = blockIdx.x;        // 0..1023
    int i = threadIdx.x;       // 0..255
    float invf = exp2f(-(float)i * (13.287712379549449f / 256.0f));
    float ang  = (float)j * invf;
    peb[j * 512 + i]       = f2bf(sinf(ang));
    peb[j * 512 + 256 + i] = f2bf(cosf(ang));
}

// ----------------------------------------- relb = bf16(PE @ Wr^T), MFMA
// grid 128: bm = blk>>3 (64-row j tile), bn = blk&7 (64-col e tile = head bn)
__global__ __launch_bounds__(256) void rel_kernel(const unsigned short* __restrict__ peb,
                                                  const float* __restrict__ Wr,
                                                  unsigned short* __restrict__ relb) {
    __shared__ __align__(16) unsigned short At[64][64];
    __shared__ __align__(16) unsigned short Bt[64][64];
    int bm = blockIdx.x >> 3, bn = blockIdx.x & 7;
    int tid = threadIdx.x;
    int w = tid >> 6, lane = tid & 63;
    int fr = lane & 15, fg = lane >> 4;
    f32x4 acc[4] = {};
    for (int kk = 0; kk < 512; kk += 64) {
        __syncthreads();
        for (int p = 0; p < 2; ++p) {
            int idx = tid + 256 * p;              // 0..511
            int row = idx >> 3, slot = idx & 7;
            *(bf16x8*)&At[row][((slot ^ (row & 7))) * 8] =
                *(const bf16x8*)&peb[(bm * 64 + row) * 512 + kk + slot * 8];
        }
        for (int p = 0; p < 4; ++p) {
            int idx = tid + 256 * p;              // 0..1023 = 64 rows x 16 float4
            int row = idx >> 4, c4 = idx & 15;
            float4 v = *(const float4*)&Wr[(bn * 64 + row) * 512 + kk + c4 * 4];
            ushort4v pk;
            pk[0] = f2bf(v.x); pk[1] = f2bf(v.y); pk[2] = f2bf(v.z); pk[3] = f2bf(v.w);
            int slot = c4 >> 1, rem = (c4 & 1) * 4;
            *(ushort4v*)&Bt[row][((slot ^ (row & 7))) * 8 + rem] = pk;
        }
        __syncthreads();
        bf16x8 af[2];
        int ar = w * 16 + fr;
#pragma unroll
        for (int s = 0; s < 2; ++s)
            af[s] = *(const bf16x8*)&At[ar][((fg + 4 * s) ^ (ar & 7)) * 8];
#pragma unroll
        for (int c = 0; c < 4; ++c) {
            int br = c * 16 + fr;
#pragma unroll
            for (int s = 0; s < 2; ++s) {
                bf16x8 bf = *(const bf16x8*)&Bt[br][((fg + 4 * s) ^ (br & 7)) * 8];
                acc[c] = MFMA16(af[s], bf, acc[c], 0, 0, 0);
            }
        }
    }
#pragma unroll
    for (int c = 0; c < 4; ++c)
#pragma unroll
        for (int i = 0; i < 4; ++i)
            relb[(bn * 1024 + bm * 64 + w * 16 + fg * 4 + i) * 64 + c * 16 + fr] =
                f2bf(acc[c][i]);
}

// ------------------------------------------------- q/k/v head projections, MFMA
// grid 256: n = blk>>4, t0 = (blk&15)*32; 256 threads = 4 waves; wave w -> heads 2w,2w+1
__global__ __launch_bounds__(256) void proj_kernel(const float* __restrict__ query,
                                                   const float* __restrict__ keys,
                                                   const float* __restrict__ values,
                                                   const float* __restrict__ Wq,
                                                   const float* __restrict__ Wk,
                                                   const float* __restrict__ Wv,
                                                   const float* __restrict__ u_bias,
                                                   const float* __restrict__ v_bias,
                                                   float* __restrict__ ws) {
    __shared__ __align__(16) unsigned short inb[32][512];     // 32 KB
    __shared__ __align__(16) unsigned short Wb[3][64][64];    // 24 KB
    __shared__ __align__(16) unsigned short vtile[4][64][36]; // 18 KB
    int n = blockIdx.x >> 4, t0 = (blockIdx.x & 15) * 32;
    int tid = threadIdx.x;
    int w = tid >> 6, lane = tid & 63;
    int fr = lane & 15, fg = lane >> 4;

    for (int p = 0; p < 3; ++p) {
        const float* Wp = (p == 0) ? Wq : (p == 1) ? Wk : Wv;
        for (int it = 0; it < 4; ++it) {
            int idx = tid + 256 * it;            // 0..1023 = 64 rows x 16 float4
            int row = idx >> 4, c4 = idx & 15;
            float4 v = *(const float4*)&Wp[row * 64 + c4 * 4];
            ushort4v pk;
            pk[0] = f2bf(v.x); pk[1] = f2bf(v.y); pk[2] = f2bf(v.z); pk[3] = f2bf(v.w);
            int slot = c4 >> 1, rem = (c4 & 1) * 4;
            *(ushort4v*)&Wb[p][row][((slot ^ (row & 7))) * 8 + rem] = pk;
        }
    }
    unsigned short* qu_b = (unsigned short*)(ws + WS_QU);
    unsigned short* qv_b = (unsigned short*)(ws + WS_QV);
    unsigned short* k_b  = (unsigned short*)(ws + WS_KB);
    unsigned short* vT_b = (unsigned short*)(ws + WS_VT);

    for (int p = 0; p < 3; ++p) {
        const float* src = (p == 0) ? query : (p == 1) ? keys : values;
        __syncthreads();                         // Wb ready / inb WAR
        for (int it = 0; it < 16; ++it) {
            int idx = tid + 256 * it;            // 0..4095 = 32 rows x 128 float4
            int row = idx >> 7, c4 = idx & 127;
            float4 v = *(const float4*)&src[((long)(n * 512 + t0 + row)) * 512 + c4 * 4];
            ushort4v pk;
            pk[0] = f2bf(v.x); pk[1] = f2bf(v.y); pk[2] = f2bf(v.z); pk[3] = f2bf(v.w);
            int slot = c4 >> 1, rem = (c4 & 1) * 4;
            *(ushort4v*)&inb[row][((slot ^ (row & 7))) * 8 + rem] = pk;
        }
        __syncthreads();
        for (int hh = 0; hh < 2; ++hh) {
            int h = w * 2 + hh, nh = n * 8 + h;
            bf16x8 af[2][2];
#pragma unroll
            for (int tt = 0; tt < 2; ++tt) {
                int ar = tt * 16 + fr;
#pragma unroll
                for (int s = 0; s < 2; ++s)
                    af[tt][s] = *(const bf16x8*)&inb[ar][(h * 8 + ((fg + 4 * s) ^ (ar & 7))) * 8];
            }
            f32x4 acc[2][4] = {};
#pragma unroll
            for (int dt = 0; dt < 4; ++dt) {
                int br = dt * 16 + fr;
                bf16x8 bf[2];
#pragma unroll
                for (int s = 0; s < 2; ++s)
                    bf[s] = *(const bf16x8*)&Wb[p][br][((fg + 4 * s) ^ (br & 7)) * 8];
#pragma unroll
                for (int tt = 0; tt < 2; ++tt)
#pragma unroll
                    for (int s = 0; s < 2; ++s)
                        acc[tt][dt] = MFMA16(af[tt][s], bf[s], acc[tt][dt], 0, 0, 0);
            }
            if (p == 0) {
#pragma unroll
                for (int dt = 0; dt < 4; ++dt) {
                    float ub = u_bias[h * 64 + dt * 16 + fr];
                    float vb = v_bias[h * 64 + dt * 16 + fr];
#pragma unroll
                    for (int tt = 0; tt < 2; ++tt)
#pragma unroll
                        for (int i = 0; i < 4; ++i) {
                            long o = ((long)(nh * 512 + t0 + tt * 16 + fg * 4 + i)) * 64 +
                                     dt * 16 + fr;
                            qu_b[o] = f2bf(acc[tt][dt][i] + ub);
                            qv_b[o] = f2bf(acc[tt][dt][i] + vb);
                        }
                }
            } else if (p == 1) {
#pragma unroll
                for (int dt = 0; dt < 4; ++dt)
#pragma unroll
                    for (int tt = 0; tt < 2; ++tt)
#pragma unroll
                        for (int i = 0; i < 4; ++i)
                            k_b[((long)(nh * 512 + t0 + tt * 16 + fg * 4 + i)) * 64 +
                                dt * 16 + fr] = f2bf(acc[tt][dt][i]);
            } else {
                // transpose via per-wave LDS tile, then coalesced vT store
#pragma unroll
                for (int dt = 0; dt < 4; ++dt)
#pragma unroll
                    for (int tt = 0; tt < 2; ++tt)
#pragma unroll
                        for (int i = 0; i < 4; ++i)
                            vtile[w][dt * 16 + fr][tt * 16 + fg * 4 + i] =
                                f2bf(acc[tt][dt][i]);
                __syncthreads();
#pragma unroll
                for (int dg = 0; dg < 8; ++dg) {
                    int d = dg * 8 + (lane >> 3), tq = lane & 7;
                    *(ushort4v*)&vT_b[((long)(nh * 64 + d)) * 512 + t0 + tq * 4] =
                        *(const ushort4v*)&vtile[w][d][tq * 4];
                }
                __syncthreads();
            }
        }
    }
}

// ------------------------------------------- fused MFMA scores+softmax+PV
// one block per (n, h, q-tile of 32); 512 threads = 8 waves; 2 blocks/CU
__global__ __launch_bounds__(512) void attn_kernel(float* __restrict__ ws,
                                                   const int* __restrict__ mask,
                                                   float* __restrict__ d_out) {
    __shared__ __align__(16) float S[32][516];   // 66048 B

    const unsigned short* qu_b = (const unsigned short*)(ws + WS_QU);
    const unsigned short* qv_b = (const unsigned short*)(ws + WS_QV);
    const unsigned short* k_b  = (const unsigned short*)(ws + WS_KB);
    const unsigned short* vT_b = (const unsigned short*)(ws + WS_VT);
    const unsigned short* relb = (const unsigned short*)(ws + WS_RELB);
    unsigned short* ohb = (unsigned short*)(ws + WS_OH);
    float* attn = d_out + 4194304;               // [N][H][Q][K]

    int blk = blockIdx.x;
    int n  = blk >> 7;
    int h  = (blk >> 4) & 7;
    int q0 = (blk & 15) * 32;
    int nh = n * 8 + h;

    int tid  = threadIdx.x;
    int w    = tid >> 6, lane = tid & 63;
    int fr   = lane & 15, fg = lane >> 4;

    // q fragments for BOTH 16-row q-tiles (direct load)
    bf16x8 quf[2][2], qvf[2][2];
#pragma unroll
    for (int qt = 0; qt < 2; ++qt) {
        long qb = ((long)(nh * 512 + q0 + qt * 16 + fr)) * 64;
#pragma unroll
        for (int s = 0; s < 2; ++s) {
            quf[qt][s] = *(const bf16x8*)&qu_b[qb + (fg + 4 * s) * 8];
            qvf[qt][s] = *(const bf16x8*)&qv_b[qb + (fg + 4 * s) * 8];
        }
    }

    // ---- content: S[r][k] = (q+u).k ; wave w covers k-strip [w*64, w*64+64)
    {
        const unsigned short* kbase = k_b + (long)nh * 512 * 64;
        f32x4 acc[2][4] = {};
#pragma unroll
        for (int t = 0; t < 4; ++t) {
            int kcol = w * 64 + t * 16 + fr;
            const unsigned short* kp = kbase + (long)kcol * 64;
            bf16x8 b0 = *(const bf16x8*)&kp[fg * 8];
            bf16x8 b1 = *(const bf16x8*)&kp[(fg + 4) * 8];
#pragma unroll
            for (int qt = 0; qt < 2; ++qt) {
                acc[qt][t] = MFMA16(quf[qt][0], b0, acc[qt][t], 0, 0, 0);
                acc[qt][t] = MFMA16(quf[qt][1], b1, acc[qt][t], 0, 0, 0);
            }
        }
#pragma unroll
        for (int qt = 0; qt < 2; ++qt)
#pragma unroll
            for (int t = 0; t < 4; ++t) {
                int kcol = w * 64 + t * 16 + fr;
                int rb = qt * 16 + fg * 4;
#pragma unroll
                for (int i = 0; i < 4; ++i) S[rb + i][kcol] = acc[qt][t][i];
            }
    }
    __syncthreads();

    // ---- position: S[r][k] += (q+v).rel[j], k = r + 511 - jj
    // 34 jj-tiles of 16 over window jj in [0,543]; wave w takes jt = w, w+8, ...
    {
        const unsigned short* rbase = relb + (long)h * 1024 * 64;
        for (int jt = w; jt < 34; jt += 8) {
            int jj = jt * 16 + fr;
            int j = q0 + 1 + jj;                 // <= 448+1+543 = 992 < 1024 always
            const unsigned short* rp = rbase + (long)j * 64;
            bf16x8 b0 = *(const bf16x8*)&rp[fg * 8];
            bf16x8 b1 = *(const bf16x8*)&rp[(fg + 4) * 8];
#pragma unroll
            for (int qt = 0; qt < 2; ++qt) {
                f32x4 acc = {0.f, 0.f, 0.f, 0.f};
                acc = MFMA16(qvf[qt][0], b0, acc, 0, 0, 0);
                acc = MFMA16(qvf[qt][1], b1, acc, 0, 0, 0);
#pragma unroll
                for (int i = 0; i < 4; ++i) {
                    int r = qt * 16 + fg * 4 + i;
                    int k = r + 511 - jj;
                    if ((unsigned)k < 512u) S[r][k] += acc[i];
                }
            }
        }
    }
    __syncthreads();

    // ---- mask + scale + softmax; write attn; leave P (f32) in S
    for (int rr = 0; rr < 4; ++rr) {
        int r = w * 4 + rr;
        const int* mrow = mask + ((long)(n * 512 + q0 + r)) * 512;
        float lg[8];
        float mx = -3.0e38f;
#pragma unroll
        for (int j = 0; j < 8; ++j) {
            int k = lane + 64 * j;
            float s = S[r][k];
            int m = mrow[k];
            float l = (m == 0) ? -1.25e19f : s * 0.125f;
            lg[j] = l;
            mx = fmaxf(mx, l);
        }
        for (int o = 32; o > 0; o >>= 1) mx = fmaxf(mx, __shfl_xor(mx, o, 64));
        float sum = 0.f;
#pragma unroll
        for (int j = 0; j < 8; ++j) { lg[j] = __expf(lg[j] - mx); sum += lg[j]; }
        for (int o = 32; o > 0; o >>= 1) sum += __shfl_xor(sum, o, 64);
        float inv = 1.0f / sum;
        float* arow = attn + ((long)(nh * 512 + q0 + r)) * 512;
#pragma unroll
        for (int j = 0; j < 8; ++j) {
            int k = lane + 64 * j;
            float p = lg[j] * inv;
            S[r][k] = p;
            arow[k] = p;
        }
    }
    __syncthreads();

    // ---- PV: oh[q][d] = P.v ; wave -> (q-tile w&1, d-tile w>>1)
    {
        int qt = w & 1, dt = w >> 1;
        const unsigned short* vp0 = vT_b + ((long)(nh * 64 + dt * 16 + fr)) * 512;
        f32x4 oacc = {0.f, 0.f, 0.f, 0.f};
#pragma unroll
        for (int kk = 0; kk < 16; ++kk) {
            const float* sp = &S[qt * 16 + fr][kk * 32 + fg * 8];
            f32x4 a = *(const f32x4*)sp;
            f32x4 b = *(const f32x4*)(sp + 4);
            bf16x8 pk;
            pk[0] = f2bf(a.x); pk[1] = f2bf(a.y); pk[2] = f2bf(a.z); pk[3] = f2bf(a.w);
            pk[4] = f2bf(b.x); pk[5] = f2bf(b.y); pk[6] = f2bf(b.z); pk[7] = f2bf(b.w);
            bf16x8 bf = *(const bf16x8*)&vp0[kk * 32 + fg * 8];
            oacc = MFMA16(pk, bf, oacc, 0, 0, 0);
        }
#pragma unroll
        for (int i = 0; i < 4; ++i)
            ohb[((long)(n * 512 + q0 + qt * 16 + fg * 4 + i)) * 512 +
                h * 64 + dt * 16 + fr] = f2bf(oacc[i]);
    }
}

// ----------------------- out = oh @ Wo^T + bo  (bf16 MFMA, f32 epilogue)
__global__ __launch_bounds__(256) void wo_kernel(const float* __restrict__ ws,
                                                 const float* __restrict__ Wo,
                                                 const float* __restrict__ bo,
                                                 float* __restrict__ d_out) {
    __shared__ __align__(16) unsigned short At[128][64];   // 16 KB
    __shared__ __align__(16) unsigned short Bt[64][64];    // 8 KB
    const unsigned short* ohb = (const unsigned short*)(ws + WS_OH);
    int bm = blockIdx.x >> 3, bn = blockIdx.x & 7;
    int tid = threadIdx.x;
    int w = tid >> 6, lane = tid & 63;
    int fr = lane & 15, fg = lane >> 4;
    f32x4 acc[2][4] = {};
    for (int kk = 0; kk < 512; kk += 64) {
        __syncthreads();
        for (int p = 0; p < 4; ++p) {
            int idx = tid + 256 * p;       // 0..1023
            int row = idx >> 3, slot = idx & 7;
            *(bf16x8*)&At[row][((slot ^ (row & 7))) * 8] =
                *(const bf16x8*)&ohb[(long)(bm * 128 + row) * 512 + kk + slot * 8];
        }
        for (int p = 0; p < 2; ++p) {
            int idx = tid + 256 * p;       // 0..511
            int row = idx >> 3, slot = idx & 7;
            const float* g = &Wo[(bn * 64 + row) * 512 + kk + slot * 8];
            float4 a = *(const float4*)g;
            float4 b = *(const float4*)(g + 4);
            ushort8v pk;
            pk[0] = f2bf(a.x); pk[1] = f2bf(a.y); pk[2] = f2bf(a.z); pk[3] = f2bf(a.w);
            pk[4] = f2bf(b.x); pk[5] = f2bf(b.y); pk[6] = f2bf(b.z); pk[7] = f2bf(b.w);
            *(ushort8v*)&Bt[row][((slot ^ (row & 7))) * 8] = pk;
        }
        __syncthreads();
        bf16x8 af[2][2], bfr[4][2];
#pragma unroll
        for (int t = 0; t < 2; ++t) {
            int ar = w * 32 + t * 16 + fr;
#pragma unroll
            for (int s = 0; s < 2; ++s)
                af[t][s] = *(const bf16x8*)&At[ar][((fg + s * 4) ^ (ar & 7)) * 8];
        }
#pragma unroll
        for (int c = 0; c < 4; ++c) {
            int br = c * 16 + fr;
#pragma unroll
            for (int s = 0; s < 2; ++s)
                bfr[c][s] = *(const bf16x8*)&Bt[br][((fg + s * 4) ^ (br & 7)) * 8];
        }
#pragma unroll
        for (int t = 0; t < 2; ++t)
#pragma unroll
            for (int c = 0; c < 4; ++c)
#pragma unroll
                for (int s = 0; s < 2; ++s)
                    acc[t][c] = MFMA16(af[t][s], bfr[c][s], acc[t][c], 0, 0, 0);
    }
#pragma unroll
    for (int t = 0; t < 2; ++t)
#pragma unroll
        for (int c = 0; c < 4; ++c) {
            int col = bn * 64 + c * 16 + fr;
            float b = bo[col];
#pragma unroll
            for (int i = 0; i < 4; ++i) {
                int row = bm * 128 + w * 32 + t * 16 + fg * 4 + i;
                d_out[(long)row * 512 + col] = acc[t][c][i] + b;
            }
        }
}

extern "C" void kernel_launch(void* const* d_in, const int* in_sizes, int n_in,
                              void* d_out, int out_size, void* d_ws, size_t ws_size,
                              hipStream_t stream) {
    const float* values = (const float*)d_in[0];
    const float* keys   = (const float*)d_in[1];
    const float* query  = (const float*)d_in[2];
    const int*   mask   = (const int*)d_in[3];
    const float* Wv     = (const float*)d_in[4];
    const float* Wk     = (const float*)d_in[5];
    const float* Wq     = (const float*)d_in[6];
    const float* Wr     = (const float*)d_in[7];
    const float* u_bias = (const float*)d_in[8];
    const float* v_bias = (const float*)d_in[9];
    const float* Wo     = (const float*)d_in[10];
    const float* bo     = (const float*)d_in[11];
    float* out = (float*)d_out;
    float* ws  = (float*)d_ws;

    unsigned short* peb  = (unsigned short*)(ws + WS_PEB);
    unsigned short* relb = (unsigned short*)(ws + WS_RELB);

    hipLaunchKernelGGL(pe_kernel,   dim3(1024),  dim3(256), 0, stream, peb);
    hipLaunchKernelGGL(rel_kernel,  dim3(128),   dim3(256), 0, stream, peb, Wr, relb);
    hipLaunchKernelGGL(proj_kernel, dim3(256),   dim3(256), 0, stream,
                       query, keys, values, Wq, Wk, Wv, u_bias, v_bias, ws);
    hipLaunchKernelGGL(attn_kernel, dim3(2048),  dim3(512), 0, stream, ws, mask, out);
    hipLaunchKernelGGL(wo_kernel,   dim3(512),   dim3(256), 0, stream, ws, Wo, bo, out);
}